// Round 1
// baseline (671.033 us; speedup 1.0000x reference)
//
#include <hip/hip_runtime.h>
#include <cstdint>
#include <cstddef>

typedef unsigned short bf16t;

// ---------- helpers ----------
__device__ __forceinline__ unsigned short f2bf(float f) {
    unsigned u = __float_as_uint(f);
    u += 0x7fffu + ((u >> 16) & 1u);   // RNE
    return (unsigned short)(u >> 16);
}
__device__ __forceinline__ float bf2f(unsigned short h) {
    return __uint_as_float(((unsigned)h) << 16);
}
__device__ __forceinline__ float bflo(unsigned u) { return __uint_as_float(u << 16); }
__device__ __forceinline__ float bfhi(unsigned u) { return __uint_as_float(u & 0xffff0000u); }

// order-preserving float<->uint encoding for atomicMax
__device__ __forceinline__ unsigned fenc(float f) {
    unsigned u = __float_as_uint(f);
    return (u & 0x80000000u) ? ~u : (u | 0x80000000u);
}
__device__ __forceinline__ float fdec(unsigned u) {
    return __uint_as_float((u & 0x80000000u) ? (u ^ 0x80000000u) : ~u);
}

#define HW 65536
#define NPIX 256

// ---------- K1: 1x1 conv producing q (8ch), k (8ch), v (64ch, bf16) ----------
// grid (4, 64, B); block 256; tile = 4h x 64w
__global__ __launch_bounds__(256) void conv_qkv(
    const float* __restrict__ x,
    const float* __restrict__ wq, const float* __restrict__ bq,
    const float* __restrict__ wk, const float* __restrict__ bk,
    const float* __restrict__ wv, const float* __restrict__ bv,
    float* __restrict__ q, float* __restrict__ k, bf16t* __restrict__ v)
{
    const int t = threadIdx.x;
    const int b = blockIdx.z;
    const int h = blockIdx.y * 4 + (t >> 6);
    const int w = blockIdx.x * 64 + (t & 63);
    const int pix = h * 256 + w;

    float qa[8], ka[8], va[64];
#pragma unroll
    for (int o = 0; o < 8; o++) { qa[o] = bq[o]; ka[o] = bk[o]; }
#pragma unroll
    for (int o = 0; o < 64; o++) va[o] = bv[o];

    const float* xb = x + (size_t)b * 64 * HW + pix;
    for (int c = 0; c < 64; c++) {
        const float xv = xb[(size_t)c * HW];
#pragma unroll
        for (int o = 0; o < 8; o++) { qa[o] += wq[o * 64 + c] * xv; ka[o] += wk[o * 64 + c] * xv; }
#pragma unroll
        for (int o = 0; o < 64; o++) va[o] += wv[o * 64 + c] * xv;
    }
    float* qo = q + (size_t)b * 8 * HW + pix;
    float* ko = k + (size_t)b * 8 * HW + pix;
    bf16t* vo = v + (size_t)b * 64 * HW + pix;
#pragma unroll
    for (int o = 0; o < 8; o++) { qo[(size_t)o * HW] = qa[o]; ko[(size_t)o * HW] = ka[o]; }
#pragma unroll
    for (int o = 0; o < 64; o++) vo[(size_t)o * HW] = f2bf(va[o]);
}

// ---------- transposes: per-slice 256x256, 64x64 tiles ----------
__global__ __launch_bounds__(256) void transpose32(const float* __restrict__ in, float* __restrict__ out)
{
    __shared__ float tile[64][65];
    const size_t zo = (size_t)blockIdx.z * HW;
    const int i0 = blockIdx.y * 64, j0 = blockIdx.x * 64;
    const int lc = threadIdx.x & 63, rg = threadIdx.x >> 6;
#pragma unroll
    for (int rr = 0; rr < 16; rr++) {
        int row = rg * 16 + rr;
        tile[row][lc] = in[zo + (size_t)(i0 + row) * 256 + j0 + lc];
    }
    __syncthreads();
#pragma unroll
    for (int rr = 0; rr < 16; rr++) {
        int row = rg * 16 + rr;
        out[zo + (size_t)(j0 + row) * 256 + i0 + lc] = tile[lc][row];
    }
}

__global__ __launch_bounds__(256) void transpose16(const bf16t* __restrict__ in, bf16t* __restrict__ out)
{
    __shared__ bf16t tile[64][68];
    const size_t zo = (size_t)blockIdx.z * HW;
    const int i0 = blockIdx.y * 64, j0 = blockIdx.x * 64;
    const int lc = threadIdx.x & 63, rg = threadIdx.x >> 6;
#pragma unroll
    for (int rr = 0; rr < 16; rr++) {
        int row = rg * 16 + rr;
        tile[row][lc] = in[zo + (size_t)(i0 + row) * 256 + j0 + lc];
    }
    __syncthreads();
#pragma unroll
    for (int rr = 0; rr < 16; rr++) {
        int row = rg * 16 + rr;
        out[zo + (size_t)(j0 + row) * 256 + i0 + lc] = tile[lc][row];
    }
}

// ---------- K2/K3: one row of criss-cross attention (online softmax) ----------
// grid (256 rows, B); block 256.  Computes, for row r:
//   e[w][j] = dot8(q[:,r,w], k[:,r,j])   (diag j==w masked if MASK)
//   m[w]=max, s[w]=sum exp, outP[c][w] = sum_j exp(e-m) * v[c][r][j]   (unnormalized)
template <bool MASK>
__global__ __launch_bounds__(256) void rowcc(
    const float* __restrict__ q, const float* __restrict__ k, const bf16t* __restrict__ v,
    bf16t* __restrict__ outP, float* __restrict__ mOut, float* __restrict__ sOut)
{
    __shared__ float ks[256][8];
    __shared__ __align__(16) bf16t vs[256][72];   // [j][c], padded row 144B
    __shared__ __align__(16) bf16t ps[32][256];   // [j within tile][w]
    __shared__ float alphas[256];

    const int t = threadIdx.x;
    const int r = blockIdx.x, b = blockIdx.y;

    const size_t qb = (size_t)b * 8 * HW + (size_t)r * 256 + t;
    float qr[8];
#pragma unroll
    for (int c = 0; c < 8; c++) qr[c] = q[qb + (size_t)c * HW];
#pragma unroll
    for (int c = 0; c < 8; c++) ks[t][c] = k[qb + (size_t)c * HW];
    const size_t vb = (size_t)b * 64 * HW + (size_t)r * 256 + t;
#pragma unroll
    for (int c = 0; c < 64; c++) vs[t][c] = v[vb + (size_t)c * HW];

    float m_t = -3.0e38f, s_t = 0.f;
    float acc[8][8];
#pragma unroll
    for (int i = 0; i < 8; i++)
#pragma unroll
        for (int j = 0; j < 8; j++) acc[i][j] = 0.f;
    const int w0 = (t >> 3) * 8, c0 = (t & 7) * 8;
    __syncthreads();

    for (int jt = 0; jt < 8; jt++) {
        const int j0 = jt * 32;
        // --- scores for this thread's w (= t) over j0..j0+31 ---
        float ev[32];
        float tmax = -3.0e38f;
#pragma unroll
        for (int j = 0; j < 32; j++) {
            const int jj = j0 + j;
            const float4 ka0 = *(const float4*)&ks[jj][0];
            const float4 ka1 = *(const float4*)&ks[jj][4];
            float e = qr[0] * ka0.x + qr[1] * ka0.y + qr[2] * ka0.z + qr[3] * ka0.w
                    + qr[4] * ka1.x + qr[5] * ka1.y + qr[6] * ka1.z + qr[7] * ka1.w;
            ev[j] = e;
            if (!(MASK && jj == t)) tmax = fmaxf(tmax, e);
        }
        const float m_new = fmaxf(m_t, tmax);
        const float alpha = __expf(m_t - m_new);
        s_t *= alpha;
        float ps_sum = 0.f;
#pragma unroll
        for (int j = 0; j < 32; j++) {
            const int jj = j0 + j;
            const float pj = (MASK && jj == t) ? 0.f : __expf(ev[j] - m_new);
            ps_sum += pj;
            ps[j][t] = f2bf(pj);
        }
        s_t += ps_sum;
        alphas[t] = alpha;
        m_t = m_new;
        __syncthreads();

        // --- PV: thread tile 8w x 8c ---
        float al[8];
#pragma unroll
        for (int wi = 0; wi < 8; wi++) al[wi] = alphas[w0 + wi];
#pragma unroll
        for (int wi = 0; wi < 8; wi++)
#pragma unroll
            for (int ci = 0; ci < 8; ci++) acc[wi][ci] *= al[wi];

#pragma unroll 4
        for (int j = 0; j < 32; j++) {
            const uint4 pu = *(const uint4*)&ps[j][w0];
            const uint4 vu = *(const uint4*)&vs[j][c0];
            float pw[8], vc[8];
            pw[0] = bflo(pu.x); pw[1] = bfhi(pu.x);
            pw[2] = bflo(pu.y); pw[3] = bfhi(pu.y);
            pw[4] = bflo(pu.z); pw[5] = bfhi(pu.z);
            pw[6] = bflo(pu.w); pw[7] = bfhi(pu.w);
            vc[0] = bflo(vu.x); vc[1] = bfhi(vu.x);
            vc[2] = bflo(vu.y); vc[3] = bfhi(vu.y);
            vc[4] = bflo(vu.z); vc[5] = bfhi(vu.z);
            vc[6] = bflo(vu.w); vc[7] = bfhi(vu.w);
#pragma unroll
            for (int wi = 0; wi < 8; wi++)
#pragma unroll
                for (int ci = 0; ci < 8; ci++) acc[wi][ci] += pw[wi] * vc[ci];
        }
        __syncthreads();
    }

    mOut[(size_t)b * HW + r * 256 + t] = m_t;
    sOut[(size_t)b * HW + r * 256 + t] = s_t;

    bf16t* ob = outP + (size_t)b * 64 * HW + (size_t)r * 256 + w0;
#pragma unroll
    for (int ci = 0; ci < 8; ci++) {
        unsigned short u[8];
#pragma unroll
        for (int wi = 0; wi < 8; wi++) u[wi] = f2bf(acc[wi][ci]);
        uint4 pk;
        pk.x = u[0] | ((unsigned)u[1] << 16);
        pk.y = u[2] | ((unsigned)u[3] << 16);
        pk.z = u[4] | ((unsigned)u[5] << 16);
        pk.w = u[6] | ((unsigned)u[7] << 16);
        *(uint4*)(ob + (size_t)(c0 + ci) * HW) = pk;
    }
}

// ---------- K4a: per-pixel softmax merge factors for both attentions ----------
// fH = exp(mH - M)/den, fW = exp(mW - M)/den
__global__ __launch_bounds__(256) void merge_factors(
    const float* __restrict__ mH1, const float* __restrict__ sH1,
    const float* __restrict__ mW1, const float* __restrict__ sW1,
    const float* __restrict__ mH2, const float* __restrict__ sH2,
    const float* __restrict__ mW2, const float* __restrict__ sW2,
    float* __restrict__ fH1, float* __restrict__ fW1,
    float* __restrict__ fH2, float* __restrict__ fW2)
{
    const int tid = blockIdx.x * 256 + threadIdx.x;     // 0..131071
    const int b = tid >> 16, hw = tid & 65535, h = hw >> 8, w = hw & 255;
    const int tIdx = (b << 16) + (w << 8) + h;          // transposed-layout index
    {
        const float mh = mH1[tIdx], sh = sH1[tIdx], mw = mW1[tid], sw = sW1[tid];
        const float M = fmaxf(mh, mw);
        const float eh = __expf(mh - M), ew = __expf(mw - M);
        const float inv = 1.f / (sh * eh + sw * ew);
        fH1[tid] = eh * inv; fW1[tid] = ew * inv;
    }
    {
        const float mh = mH2[tIdx], sh = sH2[tIdx], mw = mW2[tid], sw = sW2[tid];
        const float M = fmaxf(mh, mw);
        const float eh = __expf(mh - M), ew = __expf(mw - M);
        const float inv = 1.f / (sh * eh + sw * ew);
        fH2[tid] = eh * inv; fW2[tid] = ew * inv;
    }
}

// ---------- K4b: combine att + residuals, write s1/s2 (bf16), reduce stats ----------
// grid (16 chunks, 64 c, 2 b)
__global__ __launch_bounds__(256) void combine_reduce(
    const bf16t* __restrict__ oH1, const bf16t* __restrict__ oW1,
    const bf16t* __restrict__ oH2, const bf16t* __restrict__ oW2,
    const float* __restrict__ fH1, const float* __restrict__ fW1,
    const float* __restrict__ fH2, const float* __restrict__ fW2,
    const float* __restrict__ x1, const float* __restrict__ x2,
    const float* __restrict__ gamma1, const float* __restrict__ gamma2,
    bf16t* __restrict__ s1, bf16t* __restrict__ s2,
    float* __restrict__ accum, unsigned* __restrict__ accmax)
{
    const int t = threadIdx.x, chunk = blockIdx.x, c = blockIdx.y, b = blockIdx.z;
    const float g1v = gamma1[0], g2v = gamma2[0];
    const size_t cb = ((size_t)(b * 64 + c)) * HW;
    const size_t pb = (size_t)b * HW;

    float pS1 = 0, pSS1 = 0, pSX1 = 0, pX1 = 0, pXX1 = 0, pM1 = -3e38f;
    float pS2 = 0, pSS2 = 0, pSX2 = 0, pX2 = 0, pXX2 = 0, pM2 = -3e38f;

    for (int i = 0; i < 16; i++) {
        const int pidx = chunk * 4096 + i * 256 + t;
        const float f_h1 = fH1[pb + pidx], f_w1 = fW1[pb + pidx];
        const float f_h2 = fH2[pb + pidx], f_w2 = fW2[pb + pidx];
        const float a1 = bf2f(oH1[cb + pidx]) * f_h1 + bf2f(oW1[cb + pidx]) * f_w1;
        const float a2 = bf2f(oH2[cb + pidx]) * f_h2 + bf2f(oW2[cb + pidx]) * f_w2;
        const float x1v = x1[cb + pidx], x2v = x2[cb + pidx];
        const float s1v = g2v * a2 + x2v + x1v;
        const float s2v = g1v * a1 + x1v + x2v;
        s1[cb + pidx] = f2bf(s1v);
        s2[cb + pidx] = f2bf(s2v);
        pS1 += s1v; pSS1 += s1v * s1v; pSX1 += s1v * x1v; pX1 += x1v; pXX1 += x1v * x1v; pM1 = fmaxf(pM1, s1v);
        pS2 += s2v; pSS2 += s2v * s2v; pSX2 += s2v * x2v; pX2 += x2v; pXX2 += x2v * x2v; pM2 = fmaxf(pM2, s2v);
    }

    __shared__ float wred[12][4];
    float vals[12] = {pS1, pSS1, pSX1, pX1, pXX1, pM1, pS2, pSS2, pSX2, pX2, pXX2, pM2};
    const int lane = t & 63, wave = t >> 6;
#pragma unroll
    for (int iv = 0; iv < 12; iv++) {
        float v = vals[iv];
        const bool isMax = (iv == 5 || iv == 11);
#pragma unroll
        for (int off = 32; off > 0; off >>= 1) {
            const float o = __shfl_down(v, off, 64);
            v = isMax ? fmaxf(v, o) : (v + o);
        }
        if (lane == 0) wred[iv][wave] = v;
    }
    __syncthreads();
    if (t < 12) {
        const bool isMax = (t == 5 || t == 11);
        float v = wred[t][0];
        for (int i = 1; i < 4; i++) v = isMax ? fmaxf(v, wred[t][i]) : (v + wred[t][i]);
        const int stream = (t >= 6) ? 1 : 0;
        const int kk = t - stream * 6;
        if (kk == 5) atomicMax(&accmax[(stream * 2 + b) * 64 + c], fenc(v));
        else atomicAdd(&accum[((stream * 2 + b) * 64 + c) * 5 + kk], v);
    }
}

// ---------- K5: gates (shareca MLP) + analytic BN coefficients ----------
// one block, 256 threads; t = (stream*2 + b)*64 + c
__global__ __launch_bounds__(256) void gates_bn(
    const float* __restrict__ accum, const unsigned* __restrict__ accmax,
    const float* __restrict__ sc1_w1, const float* __restrict__ sc1_b1,
    const float* __restrict__ sc1_w2, const float* __restrict__ sc1_b2,
    const float* __restrict__ sc2_w1, const float* __restrict__ sc2_b1,
    const float* __restrict__ sc2_w2, const float* __restrict__ sc2_b2,
    const float* __restrict__ bn1_scale, const float* __restrict__ bn1_bias,
    const float* __restrict__ bn2_scale, const float* __restrict__ bn2_bias,
    float* __restrict__ gates, float* __restrict__ AB)
{
    const int t = threadIdx.x;
    const int stream = t >> 7, b = (t >> 6) & 1, c = t & 63;
    __shared__ float meanS[256], maxS[256], e1S[256], e2S[256];

    const float S = accum[t * 5 + 0], SS = accum[t * 5 + 1], SX = accum[t * 5 + 2];
    const float X = accum[t * 5 + 3], XX = accum[t * 5 + 4];
    meanS[t] = S * (1.f / 65536.f);
    maxS[t] = fdec(accmax[t]);
    __syncthreads();

    const float* w1 = stream ? sc2_w1 : sc1_w1;
    const float* b1 = stream ? sc2_b1 : sc1_b1;
    const float* w2 = stream ? sc2_w2 : sc1_w2;
    const float* b2 = stream ? sc2_b2 : sc1_b2;
    float om = b2[c], ox = b2[c];
    const int base = stream * 128 + b * 64;
#pragma unroll
    for (int r = 0; r < 4; r++) {
        float hm = b1[r], hx = b1[r];
        for (int cc = 0; cc < 64; cc++) {
            hm += w1[r * 64 + cc] * meanS[base + cc];
            hx += w1[r * 64 + cc] * maxS[base + cc];
        }
        hm = fmaxf(hm, 0.f); hx = fmaxf(hx, 0.f);
        om += w2[c * 4 + r] * hm;
        ox += w2[c * 4 + r] * hx;
    }
    const float gate = 1.f / (1.f + __expf(-(om + ox)));
    gates[t] = gate;
    e1S[t] = gate * S + X;                               // sum of y over this (b,c)
    e2S[t] = gate * gate * SS + 2.f * gate * SX + XX;    // sum of y^2
    __syncthreads();
    if (b == 0) {
        const float sumY = e1S[t] + e1S[t + 64];
        const float sumY2 = e2S[t] + e2S[t + 64];
        const float meanY = sumY * (1.f / 131072.f);
        const float varY = sumY2 * (1.f / 131072.f) - meanY * meanY;
        const float sc = stream ? bn2_scale[c] : bn1_scale[c];
        const float bi = stream ? bn2_bias[c] : bn1_bias[c];
        const float A = sc * rsqrtf(varY + 1e-5f);
        AB[stream * 128 + c] = A;
        AB[stream * 128 + 64 + c] = bi - meanY * A;
    }
}

// ---------- K6: final elementwise: y = g*s + x -> BN-affine -> relu -> mask ----------
__global__ __launch_bounds__(256) void finalize(
    const bf16t* __restrict__ s1, const bf16t* __restrict__ s2,
    const float* __restrict__ x1, const float* __restrict__ x2,
    const float* __restrict__ gates, const float* __restrict__ AB,
    float* __restrict__ out)
{
    const size_t tid = (size_t)blockIdx.x * 256 + threadIdx.x;
    const size_t idx = tid * 4;
    const int b = (int)(idx >> 22);
    const int c = (int)((idx >> 16) & 63);
    const bool odd = (c & 1) != 0;
    const float g1 = gates[b * 64 + c], g2 = gates[128 + b * 64 + c];
    const float A1 = AB[c], B1 = AB[64 + c], A2 = AB[128 + c], B2 = AB[192 + c];

    const uint2 su1 = *(const uint2*)(s1 + idx);
    const uint2 su2 = *(const uint2*)(s2 + idx);
    const float4 x1v = *(const float4*)(x1 + idx);
    const float4 x2v = *(const float4*)(x2 + idx);
    float s1f[4] = {bflo(su1.x), bfhi(su1.x), bflo(su1.y), bfhi(su1.y)};
    float s2f[4] = {bflo(su2.x), bfhi(su2.x), bflo(su2.y), bfhi(su2.y)};
    float xa[4] = {x1v.x, x1v.y, x1v.z, x1v.w};
    float xb[4] = {x2v.x, x2v.y, x2v.z, x2v.w};
    float o1[4], o2[4];
#pragma unroll
    for (int j = 0; j < 4; j++) {
        const float y1 = g1 * s1f[j] + xa[j];
        const float y2 = g2 * s2f[j] + xb[j];
        o1[j] = odd ? fmaxf(A1 * y1 + B1, 0.f) : xa[j];
        o2[j] = odd ? fmaxf(A2 * y2 + B2, 0.f) : xb[j];
    }
    *(float4*)(out + idx) = make_float4(o1[0], o1[1], o1[2], o1[3]);
    *(float4*)(out + 8388608 + idx) = make_float4(o2[0], o2[1], o2[2], o2[3]);
}

// ---------- host ----------
extern "C" void kernel_launch(void* const* d_in, const int* in_sizes, int n_in,
                              void* d_out, int out_size, void* d_ws, size_t ws_size,
                              hipStream_t stream) {
    (void)in_sizes; (void)n_in; (void)out_size; (void)ws_size;
    const float* x1 = (const float*)d_in[0];
    const float* x2 = (const float*)d_in[1];
    const float* wq1 = (const float*)d_in[2];  const float* bq1 = (const float*)d_in[3];
    const float* wq2 = (const float*)d_in[4];  const float* bq2 = (const float*)d_in[5];
    const float* wk1 = (const float*)d_in[6];  const float* bk1 = (const float*)d_in[7];
    const float* wk2 = (const float*)d_in[8];  const float* bk2 = (const float*)d_in[9];
    const float* wv1 = (const float*)d_in[10]; const float* bv1 = (const float*)d_in[11];
    const float* wv2 = (const float*)d_in[12]; const float* bv2 = (const float*)d_in[13];
    const float* gamma1 = (const float*)d_in[14];
    const float* gamma2 = (const float*)d_in[15];
    const float* sc1_w1 = (const float*)d_in[16]; const float* sc1_b1 = (const float*)d_in[17];
    const float* sc1_w2 = (const float*)d_in[18]; const float* sc1_b2 = (const float*)d_in[19];
    const float* sc2_w1 = (const float*)d_in[20]; const float* sc2_b1 = (const float*)d_in[21];
    const float* sc2_w2 = (const float*)d_in[22]; const float* sc2_b2 = (const float*)d_in[23];
    const float* bn1_scale = (const float*)d_in[24]; const float* bn1_bias = (const float*)d_in[25];
    const float* bn2_scale = (const float*)d_in[26]; const float* bn2_bias = (const float*)d_in[27];

    char* p = (char*)d_ws;
    const size_t SZ_Q = 4194304;    // fp32 (B,8,H,W)
    const size_t SZ_V = 16777216;   // bf16 (B,64,H,W)
    const size_t SZ_ST = 524288;    // fp32 (B,H,W)

    float* q1  = (float*)(p + 0 * SZ_Q);
    float* k1  = (float*)(p + 1 * SZ_Q);
    float* q2  = (float*)(p + 2 * SZ_Q);
    float* k2  = (float*)(p + 3 * SZ_Q);
    float* q1T = (float*)(p + 4 * SZ_Q);
    float* k1T = (float*)(p + 5 * SZ_Q);
    float* q2T = (float*)(p + 6 * SZ_Q);
    float* k2T = (float*)(p + 7 * SZ_Q);
    size_t off = 8 * SZ_Q;                       // 33,554,432
    bf16t* v1  = (bf16t*)(p + off); off += SZ_V;
    bf16t* v2  = (bf16t*)(p + off); off += SZ_V;
    bf16t* v1T = (bf16t*)(p + off); off += SZ_V;
    bf16t* v2T = (bf16t*)(p + off); off += SZ_V; // 100,663,296
    bf16t* oH1T = (bf16t*)(p + off); off += SZ_V;
    bf16t* oH2T = (bf16t*)(p + off); off += SZ_V; // 134,217,728
    bf16t* oW1 = (bf16t*)(p + off); off += SZ_V;
    bf16t* oW2 = (bf16t*)(p + off); off += SZ_V;  // 167,772,160
    float* mH1T = (float*)(p + off); off += SZ_ST;
    float* sH1T = (float*)(p + off); off += SZ_ST;
    float* mH2T = (float*)(p + off); off += SZ_ST;
    float* sH2T = (float*)(p + off); off += SZ_ST;
    float* mW1 = (float*)(p + off); off += SZ_ST;
    float* sW1 = (float*)(p + off); off += SZ_ST;
    float* mW2 = (float*)(p + off); off += SZ_ST;
    float* sW2 = (float*)(p + off); off += SZ_ST;
    float* fH1 = (float*)(p + off); off += SZ_ST;
    float* fW1 = (float*)(p + off); off += SZ_ST;
    float* fH2 = (float*)(p + off); off += SZ_ST;
    float* fW2 = (float*)(p + off); off += SZ_ST;
    float* accum = (float*)(p + off);                  // 2*2*64*5 floats = 5120 B
    unsigned* accmax = (unsigned*)(p + off + 5120);    // 1024 B
    float* gates = (float*)(p + off + 6144);           // 1024 B
    float* AB = (float*)(p + off + 7168);              // 1024 B

    // overlays (producers are stream-ordered before the overwrite):
    bf16t* oH1 = v1T;   // v1T dead after rowcc<true> launches
    bf16t* oH2 = v2T;
    bf16t* s1 = oH1T;   // oH1T dead after its transpose
    bf16t* s2 = oH2T;

    // K1: convs
    conv_qkv<<<dim3(4, 64, 2), 256, 0, stream>>>(x1, wq1, bq1, wk1, bk1, wv1, bv1, q1, k1, v1);
    conv_qkv<<<dim3(4, 64, 2), 256, 0, stream>>>(x2, wq2, bq2, wk2, bk2, wv2, bv2, q2, k2, v2);

    // transposes for the column pass
    transpose32<<<dim3(4, 4, 16), 256, 0, stream>>>(q1, q1T);
    transpose32<<<dim3(4, 4, 16), 256, 0, stream>>>(k1, k1T);
    transpose32<<<dim3(4, 4, 16), 256, 0, stream>>>(q2, q2T);
    transpose32<<<dim3(4, 4, 16), 256, 0, stream>>>(k2, k2T);
    transpose16<<<dim3(4, 4, 128), 256, 0, stream>>>(v1, v1T);
    transpose16<<<dim3(4, 4, 128), 256, 0, stream>>>(v2, v2T);

    // att1 = cc(q2, k1, v1); att2 = cc(q1, k2, v2)
    rowcc<true><<<dim3(256, 2), 256, 0, stream>>>(q2T, k1T, v1T, oH1T, mH1T, sH1T);
    rowcc<true><<<dim3(256, 2), 256, 0, stream>>>(q1T, k2T, v2T, oH2T, mH2T, sH2T);
    rowcc<false><<<dim3(256, 2), 256, 0, stream>>>(q2, k1, v1, oW1, mW1, sW1);
    rowcc<false><<<dim3(256, 2), 256, 0, stream>>>(q1, k2, v2, oW2, mW2, sW2);

    // bring column-pass outputs to standard layout (overwrites v1T/v2T)
    transpose16<<<dim3(4, 4, 128), 256, 0, stream>>>(oH1T, oH1);
    transpose16<<<dim3(4, 4, 128), 256, 0, stream>>>(oH2T, oH2);

    merge_factors<<<512, 256, 0, stream>>>(mH1T, sH1T, mW1, sW1, mH2T, sH2T, mW2, sW2,
                                           fH1, fW1, fH2, fW2);

    hipMemsetAsync(accum, 0, 6144, stream);

    combine_reduce<<<dim3(16, 64, 2), 256, 0, stream>>>(
        oH1, oW1, oH2, oW2, fH1, fW1, fH2, fW2, x1, x2, gamma1, gamma2,
        s1, s2, accum, accmax);

    gates_bn<<<1, 256, 0, stream>>>(accum, accmax,
                                    sc1_w1, sc1_b1, sc1_w2, sc1_b2,
                                    sc2_w1, sc2_b1, sc2_w2, sc2_b2,
                                    bn1_scale, bn1_bias, bn2_scale, bn2_bias,
                                    gates, AB);

    finalize<<<8192, 256, 0, stream>>>(s1, s2, x1, x2, gates, AB, (float*)d_out);
}

// Round 2
// 435.846 us; speedup vs baseline: 1.5396x; 1.5396x over previous
//
#include <hip/hip_runtime.h>
#include <hip/hip_bf16.h>
#include <cstdint>
#include <cstddef>

typedef unsigned short bf16t;
typedef __attribute__((ext_vector_type(8))) short bf16x8;  // 8 bf16 (4 VGPRs)
typedef __attribute__((ext_vector_type(4))) float f32x4;   // MFMA C/D

// ---------- helpers ----------
__device__ __forceinline__ unsigned short f2bf(float f) {
    unsigned u = __float_as_uint(f);
    u += 0x7fffu + ((u >> 16) & 1u);   // RNE
    return (unsigned short)(u >> 16);
}
__device__ __forceinline__ float bf2f(unsigned short h) {
    return __uint_as_float(((unsigned)h) << 16);
}
__device__ __forceinline__ float bflo(unsigned u) { return __uint_as_float(u << 16); }
__device__ __forceinline__ float bfhi(unsigned u) { return __uint_as_float(u & 0xffff0000u); }
__device__ __forceinline__ unsigned pkbf(float a, float b) {
    return (unsigned)f2bf(a) | ((unsigned)f2bf(b) << 16);
}

// order-preserving float<->uint encoding for atomicMax
__device__ __forceinline__ unsigned fenc(float f) {
    unsigned u = __float_as_uint(f);
    return (u & 0x80000000u) ? ~u : (u | 0x80000000u);
}
__device__ __forceinline__ float fdec(unsigned u) {
    return __uint_as_float((u & 0x80000000u) ? (u ^ 0x80000000u) : ~u);
}

#define HW 65536

// ---------- K1: fused 1x1 conv for both streams ----------
// grid (4, 64, 4); z = stream*2 + b; block 256; tile = 4h x 64w
struct ConvArgs {
    const float* x[2];
    const float* wq[2]; const float* bq[2];
    const float* wk[2]; const float* bk[2];
    const float* wv[2]; const float* bv[2];
    float* q[2]; float* k[2]; bf16t* v[2];
};

__global__ __launch_bounds__(256) void conv_qkv(ConvArgs A)
{
    const int t = threadIdx.x;
    const int z = blockIdx.z;
    const int s = z >> 1, b = z & 1;
    const int h = blockIdx.y * 4 + (t >> 6);
    const int w = blockIdx.x * 64 + (t & 63);
    const int pix = h * 256 + w;

    const float* wq = A.wq[s]; const float* wk = A.wk[s]; const float* wv = A.wv[s];
    float qa[8], ka[8], va[64];
#pragma unroll
    for (int o = 0; o < 8; o++) { qa[o] = A.bq[s][o]; ka[o] = A.bk[s][o]; }
#pragma unroll
    for (int o = 0; o < 64; o++) va[o] = A.bv[s][o];

    const float* xb = A.x[s] + (size_t)b * 64 * HW + pix;
    for (int c = 0; c < 64; c++) {
        const float xv = xb[(size_t)c * HW];
#pragma unroll
        for (int o = 0; o < 8; o++) { qa[o] += wq[o * 64 + c] * xv; ka[o] += wk[o * 64 + c] * xv; }
#pragma unroll
        for (int o = 0; o < 64; o++) va[o] += wv[o * 64 + c] * xv;
    }
    float* qo = A.q[s] + (size_t)b * 8 * HW + pix;
    float* ko = A.k[s] + (size_t)b * 8 * HW + pix;
    bf16t* vo = A.v[s] + (size_t)b * 64 * HW + pix;
#pragma unroll
    for (int o = 0; o < 8; o++) { qo[(size_t)o * HW] = qa[o]; ko[(size_t)o * HW] = ka[o]; }
#pragma unroll
    for (int o = 0; o < 64; o++) vo[(size_t)o * HW] = f2bf(va[o]);
}

// ---------- transposes: per-slice 256x256, 64x64 tiles, z = slice ----------
__global__ __launch_bounds__(256) void transpose32(const float* __restrict__ in, float* __restrict__ out)
{
    __shared__ float tile[64][65];
    const size_t zo = (size_t)blockIdx.z * HW;
    const int i0 = blockIdx.y * 64, j0 = blockIdx.x * 64;
    const int lc = threadIdx.x & 63, rg = threadIdx.x >> 6;
#pragma unroll
    for (int rr = 0; rr < 16; rr++) {
        int row = rg * 16 + rr;
        tile[row][lc] = in[zo + (size_t)(i0 + row) * 256 + j0 + lc];
    }
    __syncthreads();
#pragma unroll
    for (int rr = 0; rr < 16; rr++) {
        int row = rg * 16 + rr;
        out[zo + (size_t)(j0 + row) * 256 + i0 + lc] = tile[lc][row];
    }
}

__global__ __launch_bounds__(256) void transpose16(const bf16t* __restrict__ in, bf16t* __restrict__ out)
{
    __shared__ bf16t tile[64][68];
    const size_t zo = (size_t)blockIdx.z * HW;
    const int i0 = blockIdx.y * 64, j0 = blockIdx.x * 64;
    const int lc = threadIdx.x & 63, rg = threadIdx.x >> 6;
#pragma unroll
    for (int rr = 0; rr < 16; rr++) {
        int row = rg * 16 + rr;
        tile[row][lc] = in[zo + (size_t)(i0 + row) * 256 + j0 + lc];
    }
    __syncthreads();
#pragma unroll
    for (int rr = 0; rr < 16; rr++) {
        int row = rg * 16 + rr;
        out[zo + (size_t)(j0 + row) * 256 + i0 + lc] = tile[lc][row];
    }
}

// ---------- K2: fused criss-cross rows, all 4 variants, MFMA PV ----------
// grid (256 rows, B, 4 variants); block 256 (4 waves).
// Per block: scores e[w=t][j] on VALU -> online softmax -> ps[w][j] bf16 (A-layout)
//            PV via mfma_f32_16x16x32_bf16: A=P (w x k), B=V (k x c), 4 waves x 64w x 64c
struct RowccArgs {
    const float* q[4]; const float* k[4]; const bf16t* v[4];
    bf16t* o[4]; float* mo[4]; float* so[4];
};

__global__ __launch_bounds__(256, 2) void rowcc_mfma(RowccArgs P)
{
    // LDS: ks[256][8] f32 (8192) | vs[64][264] bf16 (33792) | ps[256][40] bf16 (20480) | alphas[256] f32 (1024)
    __shared__ __align__(16) char smem[63488];
    float* ks = (float*)smem;
    bf16t* vs = (bf16t*)(smem + 8192);
    bf16t* ps = (bf16t*)(smem + 8192 + 33792);
    float* alphas = (float*)(smem + 8192 + 33792 + 20480);

    const int t = threadIdx.x;
    const int r = blockIdx.x, b = blockIdx.y, z = blockIdx.z;
    const bool mask = (z < 2);
    const int lane = t & 63, wv = t >> 6, quad = lane >> 4, l16 = lane & 15;
    const int wband = wv * 64;

    const float* qp = P.q[z];
    const float* kp = P.k[z];
    const bf16t* vp = P.v[z];

    const size_t qb = (size_t)b * 8 * HW + (size_t)r * 256 + t;
    float qr[8];
#pragma unroll
    for (int c = 0; c < 8; c++) { qr[c] = qp[qb + (size_t)c * HW]; ks[t * 8 + c] = kp[qb + (size_t)c * HW]; }

    // stage V as [c][j] (row stride 264)
    const size_t vb = (size_t)b * 64 * HW + (size_t)r * 256;
#pragma unroll
    for (int i = 0; i < 8; i++) {
        const int qd = i * 256 + t;
        const int c = qd >> 5, jc = (qd & 31) * 8;
        *(uint4*)&vs[c * 264 + jc] = *(const uint4*)&vp[vb + (size_t)c * HW + jc];
    }

    float m_t = -3.0e38f, s_t = 0.f;
    const f32x4 zero4 = {0.f, 0.f, 0.f, 0.f};
    f32x4 acc[4][4];
#pragma unroll
    for (int i = 0; i < 4; i++)
#pragma unroll
        for (int j = 0; j < 4; j++) acc[i][j] = zero4;

    __syncthreads();

    for (int jt = 0; jt < 8; jt++) {
        const int j0 = jt * 32;
        float ev[32];
        float tmax = -3.0e38f;
#pragma unroll
        for (int j = 0; j < 32; j++) {
            const int jj = j0 + j;
            const float4 ka = *(const float4*)&ks[jj * 8];
            const float4 kb = *(const float4*)&ks[jj * 8 + 4];
            float e = qr[0] * ka.x + qr[1] * ka.y + qr[2] * ka.z + qr[3] * ka.w
                    + qr[4] * kb.x + qr[5] * kb.y + qr[6] * kb.z + qr[7] * kb.w;
            ev[j] = e;
            tmax = fmaxf(tmax, (mask && jj == t) ? -3.0e38f : e);
        }
        const float m_new = fmaxf(m_t, tmax);
        const float alpha = __expf(m_t - m_new);
        float psum = 0.f;
#pragma unroll
        for (int j = 0; j < 32; j++) {
            float pv = __expf(ev[j] - m_new);
            if (mask && (j0 + j) == t) pv = 0.f;
            ev[j] = pv;
            psum += pv;
        }
        s_t = s_t * alpha + psum;
        alphas[t] = alpha;
        m_t = m_new;

        bf16t* prow = ps + t * 40;
#pragma unroll
        for (int g = 0; g < 4; g++) {
            uint4 u;
            u.x = pkbf(ev[g * 8 + 0], ev[g * 8 + 1]);
            u.y = pkbf(ev[g * 8 + 2], ev[g * 8 + 3]);
            u.z = pkbf(ev[g * 8 + 4], ev[g * 8 + 5]);
            u.w = pkbf(ev[g * 8 + 6], ev[g * 8 + 7]);
            *(uint4*)(prow + g * 8) = u;
        }

        // rescale accumulators by this wave's alphas (C-layout row = quad*4+reg)
#pragma unroll
        for (int wt = 0; wt < 4; wt++) {
            const f32x4 av = *(const f32x4*)&alphas[wband + wt * 16 + quad * 4];
#pragma unroll
            for (int ct = 0; ct < 4; ct++) acc[wt][ct] *= av;
        }

        bf16x8 afr[4], bfr[4];
#pragma unroll
        for (int wt = 0; wt < 4; wt++)
            afr[wt] = *(const bf16x8*)&ps[(wband + wt * 16 + l16) * 40 + quad * 8];
#pragma unroll
        for (int ct = 0; ct < 4; ct++)
            bfr[ct] = *(const bf16x8*)&vs[(ct * 16 + l16) * 264 + j0 + quad * 8];
#pragma unroll
        for (int wt = 0; wt < 4; wt++)
#pragma unroll
            for (int ct = 0; ct < 4; ct++)
                acc[wt][ct] = __builtin_amdgcn_mfma_f32_16x16x32_bf16(afr[wt], bfr[ct], acc[wt][ct], 0, 0, 0);
    }

    P.mo[z][(size_t)b * HW + r * 256 + t] = m_t;
    P.so[z][(size_t)b * HW + r * 256 + t] = s_t;

    // epilogue: C-layout -> LDS [c][w] -> coalesced global [c][w]
    __syncthreads();
    bf16t* o_lds = (bf16t*)(smem + 8192);   // [64][264], overlays vs
#pragma unroll
    for (int wt = 0; wt < 4; wt++) {
        const int w0 = wband + wt * 16 + quad * 4;
#pragma unroll
        for (int ct = 0; ct < 4; ct++) {
            const int c = ct * 16 + l16;
            uint2 u;
            u.x = pkbf(acc[wt][ct][0], acc[wt][ct][1]);
            u.y = pkbf(acc[wt][ct][2], acc[wt][ct][3]);
            *(uint2*)&o_lds[c * 264 + w0] = u;
        }
    }
    __syncthreads();
    bf16t* ob = P.o[z] + (size_t)b * 64 * HW + (size_t)r * 256;
#pragma unroll
    for (int i = 0; i < 8; i++) {
        const int qd = i * 256 + t;
        const int c = qd >> 5, w8 = (qd & 31) * 8;
        *(uint4*)&ob[(size_t)c * HW + w8] = *(const uint4*)&o_lds[c * 264 + w8];
    }
}

// ---------- K4a: per-pixel softmax merge factors (+ zero the stat accumulators) ----------
__global__ __launch_bounds__(256) void merge_factors(
    const float* __restrict__ mH1, const float* __restrict__ sH1,
    const float* __restrict__ mW1, const float* __restrict__ sW1,
    const float* __restrict__ mH2, const float* __restrict__ sH2,
    const float* __restrict__ mW2, const float* __restrict__ sW2,
    float* __restrict__ fH1, float* __restrict__ fW1,
    float* __restrict__ fH2, float* __restrict__ fW2,
    unsigned* __restrict__ zeroRegion)
{
    if (blockIdx.x == 0) {
#pragma unroll
        for (int i = 0; i < 6; i++) zeroRegion[threadIdx.x + i * 256] = 0u;  // 1536 words = accum+accmax
    }
    const int tid = blockIdx.x * 256 + threadIdx.x;     // 0..131071
    const int b = tid >> 16, hw = tid & 65535, h = hw >> 8, w = hw & 255;
    const int tIdx = (b << 16) + (w << 8) + h;          // transposed-layout index
    {
        const float mh = mH1[tIdx], sh = sH1[tIdx], mw = mW1[tid], sw = sW1[tid];
        const float M = fmaxf(mh, mw);
        const float eh = __expf(mh - M), ew = __expf(mw - M);
        const float inv = 1.f / (sh * eh + sw * ew);
        fH1[tid] = eh * inv; fW1[tid] = ew * inv;
    }
    {
        const float mh = mH2[tIdx], sh = sH2[tIdx], mw = mW2[tid], sw = sW2[tid];
        const float M = fmaxf(mh, mw);
        const float eh = __expf(mh - M), ew = __expf(mw - M);
        const float inv = 1.f / (sh * eh + sw * ew);
        fH2[tid] = eh * inv; fW2[tid] = ew * inv;
    }
}

// ---------- K4b: combine att + residuals, write s1/s2 (bf16), reduce stats ----------
__global__ __launch_bounds__(256) void combine_reduce(
    const bf16t* __restrict__ oH1, const bf16t* __restrict__ oW1,
    const bf16t* __restrict__ oH2, const bf16t* __restrict__ oW2,
    const float* __restrict__ fH1, const float* __restrict__ fW1,
    const float* __restrict__ fH2, const float* __restrict__ fW2,
    const float* __restrict__ x1, const float* __restrict__ x2,
    const float* __restrict__ gamma1, const float* __restrict__ gamma2,
    bf16t* __restrict__ s1, bf16t* __restrict__ s2,
    float* __restrict__ accum, unsigned* __restrict__ accmax)
{
    const int t = threadIdx.x, chunk = blockIdx.x, c = blockIdx.y, b = blockIdx.z;
    const float g1v = gamma1[0], g2v = gamma2[0];
    const size_t cb = ((size_t)(b * 64 + c)) * HW;
    const size_t pb = (size_t)b * HW;

    float pS1 = 0, pSS1 = 0, pSX1 = 0, pX1 = 0, pXX1 = 0, pM1 = -3e38f;
    float pS2 = 0, pSS2 = 0, pSX2 = 0, pX2 = 0, pXX2 = 0, pM2 = -3e38f;

    for (int i = 0; i < 16; i++) {
        const int pidx = chunk * 4096 + i * 256 + t;
        const float f_h1 = fH1[pb + pidx], f_w1 = fW1[pb + pidx];
        const float f_h2 = fH2[pb + pidx], f_w2 = fW2[pb + pidx];
        const float a1 = bf2f(oH1[cb + pidx]) * f_h1 + bf2f(oW1[cb + pidx]) * f_w1;
        const float a2 = bf2f(oH2[cb + pidx]) * f_h2 + bf2f(oW2[cb + pidx]) * f_w2;
        const float x1v = x1[cb + pidx], x2v = x2[cb + pidx];
        const float s1v = g2v * a2 + x2v + x1v;
        const float s2v = g1v * a1 + x1v + x2v;
        s1[cb + pidx] = f2bf(s1v);
        s2[cb + pidx] = f2bf(s2v);
        pS1 += s1v; pSS1 += s1v * s1v; pSX1 += s1v * x1v; pX1 += x1v; pXX1 += x1v * x1v; pM1 = fmaxf(pM1, s1v);
        pS2 += s2v; pSS2 += s2v * s2v; pSX2 += s2v * x2v; pX2 += x2v; pXX2 += x2v * x2v; pM2 = fmaxf(pM2, s2v);
    }

    __shared__ float wred[12][4];
    float vals[12] = {pS1, pSS1, pSX1, pX1, pXX1, pM1, pS2, pSS2, pSX2, pX2, pXX2, pM2};
    const int lane = t & 63, wave = t >> 6;
#pragma unroll
    for (int iv = 0; iv < 12; iv++) {
        float v = vals[iv];
        const bool isMax = (iv == 5 || iv == 11);
#pragma unroll
        for (int off = 32; off > 0; off >>= 1) {
            const float o = __shfl_down(v, off, 64);
            v = isMax ? fmaxf(v, o) : (v + o);
        }
        if (lane == 0) wred[iv][wave] = v;
    }
    __syncthreads();
    if (t < 12) {
        const bool isMax = (t == 5 || t == 11);
        float v = wred[t][0];
        for (int i = 1; i < 4; i++) v = isMax ? fmaxf(v, wred[t][i]) : (v + wred[t][i]);
        const int stream = (t >= 6) ? 1 : 0;
        const int kk = t - stream * 6;
        if (kk == 5) atomicMax(&accmax[(stream * 2 + b) * 64 + c], fenc(v));
        else atomicAdd(&accum[((stream * 2 + b) * 64 + c) * 5 + kk], v);
    }
}

// ---------- K5: gates (shareca MLP) + analytic BN coefficients ----------
__global__ __launch_bounds__(256) void gates_bn(
    const float* __restrict__ accum, const unsigned* __restrict__ accmax,
    const float* __restrict__ sc1_w1, const float* __restrict__ sc1_b1,
    const float* __restrict__ sc1_w2, const float* __restrict__ sc1_b2,
    const float* __restrict__ sc2_w1, const float* __restrict__ sc2_b1,
    const float* __restrict__ sc2_w2, const float* __restrict__ sc2_b2,
    const float* __restrict__ bn1_scale, const float* __restrict__ bn1_bias,
    const float* __restrict__ bn2_scale, const float* __restrict__ bn2_bias,
    float* __restrict__ gates, float* __restrict__ AB)
{
    const int t = threadIdx.x;
    const int stream = t >> 7, b = (t >> 6) & 1, c = t & 63;
    __shared__ float meanS[256], maxS[256], e1S[256], e2S[256];

    const float S = accum[t * 5 + 0], SS = accum[t * 5 + 1], SX = accum[t * 5 + 2];
    const float X = accum[t * 5 + 3], XX = accum[t * 5 + 4];
    meanS[t] = S * (1.f / 65536.f);
    maxS[t] = fdec(accmax[t]);
    __syncthreads();

    const float* w1 = stream ? sc2_w1 : sc1_w1;
    const float* b1 = stream ? sc2_b1 : sc1_b1;
    const float* w2 = stream ? sc2_w2 : sc1_w2;
    const float* b2 = stream ? sc2_b2 : sc1_b2;
    float om = b2[c], ox = b2[c];
    const int base = stream * 128 + b * 64;
#pragma unroll
    for (int r = 0; r < 4; r++) {
        float hm = b1[r], hx = b1[r];
        for (int cc = 0; cc < 64; cc++) {
            hm += w1[r * 64 + cc] * meanS[base + cc];
            hx += w1[r * 64 + cc] * maxS[base + cc];
        }
        hm = fmaxf(hm, 0.f); hx = fmaxf(hx, 0.f);
        om += w2[c * 4 + r] * hm;
        ox += w2[c * 4 + r] * hx;
    }
    const float gate = 1.f / (1.f + __expf(-(om + ox)));
    gates[t] = gate;
    e1S[t] = gate * S + X;
    e2S[t] = gate * gate * SS + 2.f * gate * SX + XX;
    __syncthreads();
    if (b == 0) {
        const float sumY = e1S[t] + e1S[t + 64];
        const float sumY2 = e2S[t] + e2S[t + 64];
        const float meanY = sumY * (1.f / 131072.f);
        const float varY = sumY2 * (1.f / 131072.f) - meanY * meanY;
        const float sc = stream ? bn2_scale[c] : bn1_scale[c];
        const float bi = stream ? bn2_bias[c] : bn1_bias[c];
        const float A = sc * rsqrtf(varY + 1e-5f);
        AB[stream * 128 + c] = A;
        AB[stream * 128 + 64 + c] = bi - meanY * A;
    }
}

// ---------- K6: final elementwise ----------
__global__ __launch_bounds__(256) void finalize(
    const bf16t* __restrict__ s1, const bf16t* __restrict__ s2,
    const float* __restrict__ x1, const float* __restrict__ x2,
    const float* __restrict__ gates, const float* __restrict__ AB,
    float* __restrict__ out)
{
    const size_t tid = (size_t)blockIdx.x * 256 + threadIdx.x;
    const size_t idx = tid * 4;
    const int b = (int)(idx >> 22);
    const int c = (int)((idx >> 16) & 63);
    const bool odd = (c & 1) != 0;
    const float g1 = gates[b * 64 + c], g2 = gates[128 + b * 64 + c];
    const float A1 = AB[c], B1 = AB[64 + c], A2 = AB[128 + c], B2 = AB[192 + c];

    const uint2 su1 = *(const uint2*)(s1 + idx);
    const uint2 su2 = *(const uint2*)(s2 + idx);
    const float4 x1v = *(const float4*)(x1 + idx);
    const float4 x2v = *(const float4*)(x2 + idx);
    float s1f[4] = {bflo(su1.x), bfhi(su1.x), bflo(su1.y), bfhi(su1.y)};
    float s2f[4] = {bflo(su2.x), bfhi(su2.x), bflo(su2.y), bfhi(su2.y)};
    float xa[4] = {x1v.x, x1v.y, x1v.z, x1v.w};
    float xb[4] = {x2v.x, x2v.y, x2v.z, x2v.w};
    float o1[4], o2[4];
#pragma unroll
    for (int j = 0; j < 4; j++) {
        const float y1 = g1 * s1f[j] + xa[j];
        const float y2 = g2 * s2f[j] + xb[j];
        o1[j] = odd ? fmaxf(A1 * y1 + B1, 0.f) : xa[j];
        o2[j] = odd ? fmaxf(A2 * y2 + B2, 0.f) : xb[j];
    }
    *(float4*)(out + idx) = make_float4(o1[0], o1[1], o1[2], o1[3]);
    *(float4*)(out + 8388608 + idx) = make_float4(o2[0], o2[1], o2[2], o2[3]);
}

// ---------- host ----------
extern "C" void kernel_launch(void* const* d_in, const int* in_sizes, int n_in,
                              void* d_out, int out_size, void* d_ws, size_t ws_size,
                              hipStream_t stream) {
    (void)in_sizes; (void)n_in; (void)out_size; (void)ws_size;
    const float* x1 = (const float*)d_in[0];
    const float* x2 = (const float*)d_in[1];
    const float* wq1 = (const float*)d_in[2];  const float* bq1 = (const float*)d_in[3];
    const float* wq2 = (const float*)d_in[4];  const float* bq2 = (const float*)d_in[5];
    const float* wk1 = (const float*)d_in[6];  const float* bk1 = (const float*)d_in[7];
    const float* wk2 = (const float*)d_in[8];  const float* bk2 = (const float*)d_in[9];
    const float* wv1 = (const float*)d_in[10]; const float* bv1 = (const float*)d_in[11];
    const float* wv2 = (const float*)d_in[12]; const float* bv2 = (const float*)d_in[13];
    const float* gamma1 = (const float*)d_in[14];
    const float* gamma2 = (const float*)d_in[15];
    const float* sc1_w1 = (const float*)d_in[16]; const float* sc1_b1 = (const float*)d_in[17];
    const float* sc1_w2 = (const float*)d_in[18]; const float* sc1_b2 = (const float*)d_in[19];
    const float* sc2_w1 = (const float*)d_in[20]; const float* sc2_b1 = (const float*)d_in[21];
    const float* sc2_w2 = (const float*)d_in[22]; const float* sc2_b2 = (const float*)d_in[23];
    const float* bn1_scale = (const float*)d_in[24]; const float* bn1_bias = (const float*)d_in[25];
    const float* bn2_scale = (const float*)d_in[26]; const float* bn2_bias = (const float*)d_in[27];

    char* p = (char*)d_ws;
    const size_t SZ_Q = 4194304;    // fp32 (B,8,H,W)
    const size_t SZ_V = 16777216;   // bf16 (B,64,H,W)
    const size_t SZ_ST = 524288;    // fp32 (B,H,W)

    float* q1  = (float*)(p + 0 * SZ_Q);
    float* k1  = (float*)(p + 1 * SZ_Q);
    float* q2  = (float*)(p + 2 * SZ_Q);
    float* k2  = (float*)(p + 3 * SZ_Q);
    float* q1T = (float*)(p + 4 * SZ_Q);
    float* k1T = (float*)(p + 5 * SZ_Q);
    float* q2T = (float*)(p + 6 * SZ_Q);
    float* k2T = (float*)(p + 7 * SZ_Q);
    size_t off = 8 * SZ_Q;
    bf16t* v1  = (bf16t*)(p + off); off += SZ_V;
    bf16t* v2  = (bf16t*)(p + off); off += SZ_V;
    bf16t* v1T = (bf16t*)(p + off); off += SZ_V;
    bf16t* v2T = (bf16t*)(p + off); off += SZ_V;
    bf16t* oH1T = (bf16t*)(p + off); off += SZ_V;
    bf16t* oH2T = (bf16t*)(p + off); off += SZ_V;
    bf16t* oW1 = (bf16t*)(p + off); off += SZ_V;
    bf16t* oW2 = (bf16t*)(p + off); off += SZ_V;
    float* mH1T = (float*)(p + off); off += SZ_ST;
    float* sH1T = (float*)(p + off); off += SZ_ST;
    float* mH2T = (float*)(p + off); off += SZ_ST;
    float* sH2T = (float*)(p + off); off += SZ_ST;
    float* mW1 = (float*)(p + off); off += SZ_ST;
    float* sW1 = (float*)(p + off); off += SZ_ST;
    float* mW2 = (float*)(p + off); off += SZ_ST;
    float* sW2 = (float*)(p + off); off += SZ_ST;
    float* fH1 = (float*)(p + off); off += SZ_ST;
    float* fW1 = (float*)(p + off); off += SZ_ST;
    float* fH2 = (float*)(p + off); off += SZ_ST;
    float* fW2 = (float*)(p + off); off += SZ_ST;
    float* accum = (float*)(p + off);                  // 1280 floats
    unsigned* accmax = (unsigned*)(p + off + 5120);    // 256 u32 (contiguous after accum)
    float* gates = (float*)(p + off + 6144);
    float* AB = (float*)(p + off + 7168);

    // overlays (stream-ordered producers precede the overwrite):
    bf16t* oH1 = v1T;   // v1T dead after rowcc
    bf16t* oH2 = v2T;
    bf16t* s1 = oH1T;   // oH1T dead after its transpose
    bf16t* s2 = oH2T;

    // K1: fused convs
    ConvArgs CA;
    CA.x[0] = x1; CA.x[1] = x2;
    CA.wq[0] = wq1; CA.wq[1] = wq2; CA.bq[0] = bq1; CA.bq[1] = bq2;
    CA.wk[0] = wk1; CA.wk[1] = wk2; CA.bk[0] = bk1; CA.bk[1] = bk2;
    CA.wv[0] = wv1; CA.wv[1] = wv2; CA.bv[0] = bv1; CA.bv[1] = bv2;
    CA.q[0] = q1; CA.q[1] = q2; CA.k[0] = k1; CA.k[1] = k2;
    CA.v[0] = v1; CA.v[1] = v2;
    conv_qkv<<<dim3(4, 64, 4), 256, 0, stream>>>(CA);

    // transposes for the column pass (q1,k1,q2,k2 contiguous -> q1T..k2T contiguous)
    transpose32<<<dim3(4, 4, 64), 256, 0, stream>>>(q1, q1T);
    transpose16<<<dim3(4, 4, 256), 256, 0, stream>>>(v1, v1T);

    // fused criss-cross: z=0,1 column pass (masked, transposed), z=2,3 row pass
    RowccArgs RA;
    RA.q[0] = q2T; RA.k[0] = k1T; RA.v[0] = v1T; RA.o[0] = oH1T; RA.mo[0] = mH1T; RA.so[0] = sH1T;
    RA.q[1] = q1T; RA.k[1] = k2T; RA.v[1] = v2T; RA.o[1] = oH2T; RA.mo[1] = mH2T; RA.so[1] = sH2T;
    RA.q[2] = q2;  RA.k[2] = k1;  RA.v[2] = v1;  RA.o[2] = oW1;  RA.mo[2] = mW1;  RA.so[2] = sW1;
    RA.q[3] = q1;  RA.k[3] = k2;  RA.v[3] = v2;  RA.o[3] = oW2;  RA.mo[3] = mW2;  RA.so[3] = sW2;
    rowcc_mfma<<<dim3(256, 2, 4), 256, 0, stream>>>(RA);

    // column-pass outputs back to standard layout (oH1T,oH2T contiguous -> v1T,v2T contiguous)
    transpose16<<<dim3(4, 4, 256), 256, 0, stream>>>(oH1T, oH1);

    merge_factors<<<512, 256, 0, stream>>>(mH1T, sH1T, mW1, sW1, mH2T, sH2T, mW2, sW2,
                                           fH1, fW1, fH2, fW2, (unsigned*)accum);

    combine_reduce<<<dim3(16, 64, 2), 256, 0, stream>>>(
        oH1, oW1, oH2, oW2, fH1, fW1, fH2, fW2, x1, x2, gamma1, gamma2,
        s1, s2, accum, accmax);

    gates_bn<<<1, 256, 0, stream>>>(accum, accmax,
                                    sc1_w1, sc1_b1, sc1_w2, sc1_b2,
                                    sc2_w1, sc2_b1, sc2_w2, sc2_b2,
                                    bn1_scale, bn1_bias, bn2_scale, bn2_bias,
                                    gates, AB);

    finalize<<<8192, 256, 0, stream>>>(s1, s2, x1, x2, gates, AB, (float*)d_out);
}

// Round 3
// 394.790 us; speedup vs baseline: 1.6997x; 1.1040x over previous
//
#include <hip/hip_runtime.h>
#include <hip/hip_bf16.h>
#include <cstdint>
#include <cstddef>

typedef unsigned short bf16t;
typedef __attribute__((ext_vector_type(8))) short bf16x8;  // 8 bf16 (4 VGPRs)
typedef __attribute__((ext_vector_type(4))) float f32x4;   // MFMA C/D

// ---------- helpers ----------
__device__ __forceinline__ unsigned short f2bf(float f) {
    unsigned u = __float_as_uint(f);
    u += 0x7fffu + ((u >> 16) & 1u);   // RNE
    return (unsigned short)(u >> 16);
}
__device__ __forceinline__ float bf2f(unsigned short h) {
    return __uint_as_float(((unsigned)h) << 16);
}
__device__ __forceinline__ float bflo(unsigned u) { return __uint_as_float(u << 16); }
__device__ __forceinline__ float bfhi(unsigned u) { return __uint_as_float(u & 0xffff0000u); }
// packed f32x2 -> bf16x2 via v_cvt_pk_bf16_f32
__device__ __forceinline__ unsigned pk2(float a, float b) {
    __hip_bfloat162 h = __float22bfloat162_rn(make_float2(a, b));
    return *(unsigned*)&h;
}

// order-preserving float<->uint encoding for atomicMax
__device__ __forceinline__ unsigned fenc(float f) {
    unsigned u = __float_as_uint(f);
    return (u & 0x80000000u) ? ~u : (u | 0x80000000u);
}
__device__ __forceinline__ float fdec(unsigned u) {
    return __uint_as_float((u & 0x80000000u) ? (u ^ 0x80000000u) : ~u);
}

#define HW 65536

// ---------- K1: fused 1x1 conv for both streams (q,k now bf16) ----------
struct ConvArgs {
    const float* x[2];
    const float* wq[2]; const float* bq[2];
    const float* wk[2]; const float* bk[2];
    const float* wv[2]; const float* bv[2];
    bf16t* q[2]; bf16t* k[2]; bf16t* v[2];
};

__global__ __launch_bounds__(256) void conv_qkv(ConvArgs A)
{
    const int t = threadIdx.x;
    const int z = blockIdx.z;
    const int s = z >> 1, b = z & 1;
    const int h = blockIdx.y * 4 + (t >> 6);
    const int w = blockIdx.x * 64 + (t & 63);
    const int pix = h * 256 + w;

    const float* wq = A.wq[s]; const float* wk = A.wk[s]; const float* wv = A.wv[s];
    float qa[8], ka[8], va[64];
#pragma unroll
    for (int o = 0; o < 8; o++) { qa[o] = A.bq[s][o]; ka[o] = A.bk[s][o]; }
#pragma unroll
    for (int o = 0; o < 64; o++) va[o] = A.bv[s][o];

    const float* xb = A.x[s] + (size_t)b * 64 * HW + pix;
    for (int c = 0; c < 64; c++) {
        const float xv = xb[(size_t)c * HW];
#pragma unroll
        for (int o = 0; o < 8; o++) { qa[o] += wq[o * 64 + c] * xv; ka[o] += wk[o * 64 + c] * xv; }
#pragma unroll
        for (int o = 0; o < 64; o++) va[o] += wv[o * 64 + c] * xv;
    }
    bf16t* qo = A.q[s] + (size_t)b * 8 * HW + pix;
    bf16t* ko = A.k[s] + (size_t)b * 8 * HW + pix;
    bf16t* vo = A.v[s] + (size_t)b * 64 * HW + pix;
#pragma unroll
    for (int o = 0; o < 8; o++) { qo[(size_t)o * HW] = f2bf(qa[o]); ko[(size_t)o * HW] = f2bf(ka[o]); }
#pragma unroll
    for (int o = 0; o < 64; o++) vo[(size_t)o * HW] = f2bf(va[o]);
}

// ---------- bf16 transpose: per-slice 256x256, 64x64 tiles, z = slice ----------
__global__ __launch_bounds__(256) void transpose16(const bf16t* __restrict__ in, bf16t* __restrict__ out)
{
    __shared__ bf16t tile[64][68];
    const size_t zo = (size_t)blockIdx.z * HW;
    const int i0 = blockIdx.y * 64, j0 = blockIdx.x * 64;
    const int lc = threadIdx.x & 63, rg = threadIdx.x >> 6;
#pragma unroll
    for (int rr = 0; rr < 16; rr++) {
        int row = rg * 16 + rr;
        tile[row][lc] = in[zo + (size_t)(i0 + row) * 256 + j0 + lc];
    }
    __syncthreads();
#pragma unroll
    for (int rr = 0; rr < 16; rr++) {
        int row = rg * 16 + rr;
        out[zo + (size_t)(j0 + row) * 256 + i0 + lc] = tile[lc][row];
    }
}

// ---------- K2: criss-cross rows, all 4 variants, MFMA scores + MFMA PV ----------
// grid (256 rows, B, 4 variants); block 256 (4 waves).
struct RowccArgs {
    const bf16t* q[4]; const bf16t* k[4]; const bf16t* v[4];
    bf16t* o[4]; float* mo[4]; float* so[4];
};

__global__ __launch_bounds__(256) void rowcc_mfma(RowccArgs P)
{
    // LDS: ks[256][8] bf16 (4096) | qs[256][8] bf16 (4096) | vs[64][264] bf16 (33792)
    //      | ps[256][40] bf16 (20480) | alphas[256] f32 (1024)  = 63488
    __shared__ __align__(16) char smem[63488];
    bf16t* ks = (bf16t*)smem;
    bf16t* qs = (bf16t*)(smem + 4096);
    bf16t* vs = (bf16t*)(smem + 8192);
    bf16t* ps = (bf16t*)(smem + 8192 + 33792);
    float* alphas = (float*)(smem + 8192 + 33792 + 20480);

    const int t = threadIdx.x;
    const int r = blockIdx.x, b = blockIdx.y, z = blockIdx.z;
    const bool mask = (z < 2);
    const int lane = t & 63, wv = t >> 6, quad = lane >> 4, l16 = lane & 15;
    const int wband = wv * 64;

    const bf16t* qp = P.q[z];
    const bf16t* kp = P.k[z];
    const bf16t* vp = P.v[z];

    // --- stage K,Q rows (bf16, 8ch each) ---
    const size_t qb = (size_t)b * 8 * HW + (size_t)r * 256 + t;
    {
        unsigned kw[4], qw[4];
#pragma unroll
        for (int c = 0; c < 4; c++) {
            kw[c] = (unsigned)kp[qb + (size_t)(2 * c) * HW] | ((unsigned)kp[qb + (size_t)(2 * c + 1) * HW] << 16);
            qw[c] = (unsigned)qp[qb + (size_t)(2 * c) * HW] | ((unsigned)qp[qb + (size_t)(2 * c + 1) * HW] << 16);
        }
        *(uint4*)&ks[t * 8] = make_uint4(kw[0], kw[1], kw[2], kw[3]);
        *(uint4*)&qs[t * 8] = make_uint4(qw[0], qw[1], qw[2], qw[3]);
    }
    // --- stage V as [c][j] (row stride 264) ---
    const size_t vb = (size_t)b * 64 * HW + (size_t)r * 256;
#pragma unroll
    for (int i = 0; i < 8; i++) {
        const int qd = i * 256 + t;
        const int c = qd >> 5, jc = (qd & 31) * 8;
        *(uint4*)&vs[c * 264 + jc] = *(const uint4*)&vp[vb + (size_t)c * HW + jc];
    }

    const f32x4 z4 = {0.f, 0.f, 0.f, 0.f};
    f32x4 acc[4][4];
#pragma unroll
    for (int i = 0; i < 4; i++)
#pragma unroll
        for (int j = 0; j < 4; j++) acc[i][j] = z4;
    float m_t[4], s_t[4];
#pragma unroll
    for (int i = 0; i < 4; i++) { m_t[i] = -3.0e38f; s_t[i] = 0.f; }

    __syncthreads();

    // --- Q B-frags (constant over jt): B[n=w][k=ch], quads 1-3 = zero pad ---
    const bf16x8 zfr = {0, 0, 0, 0, 0, 0, 0, 0};
    bf16x8 qfr[4];
#pragma unroll
    for (int wt = 0; wt < 4; wt++) {
        bf16x8 v8 = *(const bf16x8*)&qs[(wband + wt * 16 + l16) * 8];
        qfr[wt] = (quad == 0) ? v8 : zfr;
    }

    for (int jt = 0; jt < 8; jt++) {
        const int j0 = jt * 32;
        // K A-frags: A[m=j][k=ch], quads 1-3 zero
        bf16x8 kfr[2];
#pragma unroll
        for (int jtile = 0; jtile < 2; jtile++) {
            bf16x8 v8 = *(const bf16x8*)&ks[(j0 + jtile * 16 + l16) * 8];
            kfr[jtile] = (quad == 0) ? v8 : zfr;
        }
        // scores: E[m=j][n=w]; lane: col w=l16, rows j=quad*4+reg
        f32x4 e[4][2];
#pragma unroll
        for (int wt = 0; wt < 4; wt++)
#pragma unroll
            for (int jtile = 0; jtile < 2; jtile++)
                e[wt][jtile] = __builtin_amdgcn_mfma_f32_16x16x32_bf16(kfr[jtile], qfr[wt], z4, 0, 0, 0);

        // diagonal mask (only 2 of 8 jt can contain this wave's diagonal)
        if (mask && (jt >> 1) == wv) {
#pragma unroll
            for (int wt = 0; wt < 4; wt++) {
                const int w_g = wband + wt * 16 + l16;
#pragma unroll
                for (int jtile = 0; jtile < 2; jtile++)
#pragma unroll
                    for (int rr = 0; rr < 4; rr++)
                        if (j0 + jtile * 16 + quad * 4 + rr == w_g) e[wt][jtile][rr] = -3.0e38f;
            }
        }

        // online softmax per w-column (reduce over j: in-thread 8 + cross-quad shfl)
#pragma unroll
        for (int wt = 0; wt < 4; wt++) {
            float tmax = e[wt][0][0];
#pragma unroll
            for (int jtile = 0; jtile < 2; jtile++)
#pragma unroll
                for (int rr = 0; rr < 4; rr++) tmax = fmaxf(tmax, e[wt][jtile][rr]);
            tmax = fmaxf(tmax, __shfl_xor(tmax, 16, 64));
            tmax = fmaxf(tmax, __shfl_xor(tmax, 32, 64));
            const float m_new = fmaxf(m_t[wt], tmax);
            const float alpha = __expf(m_t[wt] - m_new);
            m_t[wt] = m_new;
            float psum = 0.f;
#pragma unroll
            for (int jtile = 0; jtile < 2; jtile++) {
                float p0 = __expf(e[wt][jtile][0] - m_new);
                float p1 = __expf(e[wt][jtile][1] - m_new);
                float p2 = __expf(e[wt][jtile][2] - m_new);
                float p3 = __expf(e[wt][jtile][3] - m_new);
                psum += (p0 + p1) + (p2 + p3);
                uint2 u; u.x = pk2(p0, p1); u.y = pk2(p2, p3);
                *(uint2*)&ps[(wband + wt * 16 + l16) * 40 + jtile * 16 + quad * 4] = u;
            }
            psum += __shfl_xor(psum, 16, 64);
            psum += __shfl_xor(psum, 32, 64);
            s_t[wt] = s_t[wt] * alpha + psum;
            if (quad == 0) alphas[wband + wt * 16 + l16] = alpha;
        }

        // rescale accumulators: acc rows w = quad*4+reg
#pragma unroll
        for (int wt = 0; wt < 4; wt++) {
            const f32x4 av = *(const f32x4*)&alphas[wband + wt * 16 + quad * 4];
#pragma unroll
            for (int ct = 0; ct < 4; ct++) acc[wt][ct] *= av;
        }

        // PV: A = P (w x j), B = V (j x c)
        bf16x8 afr[4], bfr[4];
#pragma unroll
        for (int wt = 0; wt < 4; wt++)
            afr[wt] = *(const bf16x8*)&ps[(wband + wt * 16 + l16) * 40 + quad * 8];
#pragma unroll
        for (int ct = 0; ct < 4; ct++)
            bfr[ct] = *(const bf16x8*)&vs[(ct * 16 + l16) * 264 + j0 + quad * 8];
#pragma unroll
        for (int wt = 0; wt < 4; wt++)
#pragma unroll
            for (int ct = 0; ct < 4; ct++)
                acc[wt][ct] = __builtin_amdgcn_mfma_f32_16x16x32_bf16(afr[wt], bfr[ct], acc[wt][ct], 0, 0, 0);
    }

    // m/s out (transposed-frame layout, same as before); quads duplicate -> quad0 writes
    if (quad == 0) {
#pragma unroll
        for (int wt = 0; wt < 4; wt++) {
            const size_t idx = (size_t)b * HW + r * 256 + wband + wt * 16 + l16;
            P.mo[z][idx] = m_t[wt];
            P.so[z][idx] = s_t[wt];
        }
    }

    // epilogue: C-layout -> LDS [c][w] -> coalesced global [c][w]
    __syncthreads();
    bf16t* o_lds = (bf16t*)(smem + 8192);   // overlays vs
#pragma unroll
    for (int wt = 0; wt < 4; wt++) {
        const int w0 = wband + wt * 16 + quad * 4;
#pragma unroll
        for (int ct = 0; ct < 4; ct++) {
            const int c = ct * 16 + l16;
            uint2 u;
            u.x = pk2(acc[wt][ct][0], acc[wt][ct][1]);
            u.y = pk2(acc[wt][ct][2], acc[wt][ct][3]);
            *(uint2*)&o_lds[c * 264 + w0] = u;
        }
    }
    __syncthreads();
    bf16t* ob = P.o[z] + (size_t)b * 64 * HW + (size_t)r * 256;
#pragma unroll
    for (int i = 0; i < 8; i++) {
        const int qd = i * 256 + t;
        const int c = qd >> 5, w8 = (qd & 31) * 8;
        *(uint4*)&ob[(size_t)c * HW + w8] = *(const uint4*)&o_lds[c * 264 + w8];
    }
}

// ---------- K3: output transpose (z<256) fused with merge_factors (z>=256) ----------
struct TMArgs {
    const bf16t* tin; bf16t* tout;
    const float* mH1; const float* sH1; const float* mW1; const float* sW1;
    const float* mH2; const float* sH2; const float* mW2; const float* sW2;
    float* fH1; float* fW1; float* fH2; float* fW2;
    unsigned* zeroRegion;
};

__global__ __launch_bounds__(256) void transpose_merge(TMArgs M)
{
    __shared__ bf16t tile[64][68];
    const int z = blockIdx.z;
    const int t = threadIdx.x;
    if (z < 256) {
        const size_t zo = (size_t)z * HW;
        const int i0 = blockIdx.y * 64, j0 = blockIdx.x * 64;
        const int lc = t & 63, rg = t >> 6;
#pragma unroll
        for (int rr = 0; rr < 16; rr++) {
            int row = rg * 16 + rr;
            tile[row][lc] = M.tin[zo + (size_t)(i0 + row) * 256 + j0 + lc];
        }
        __syncthreads();
#pragma unroll
        for (int rr = 0; rr < 16; rr++) {
            int row = rg * 16 + rr;
            M.tout[zo + (size_t)(j0 + row) * 256 + i0 + lc] = tile[lc][row];
        }
        return;
    }
    const int mb = (z - 256) * 16 + blockIdx.y * 4 + blockIdx.x;  // 0..255
    if (mb == 0) {
#pragma unroll
        for (int i = 0; i < 6; i++) M.zeroRegion[t + i * 256] = 0u;  // accum + accmax
    }
#pragma unroll
    for (int it = 0; it < 2; it++) {
        const int tid = mb * 512 + it * 256 + t;                 // 0..131071
        const int b = tid >> 16, hw = tid & 65535, h = hw >> 8, w = hw & 255;
        const int tIdx = (b << 16) + (w << 8) + h;               // transposed-layout index
        {
            const float mh = M.mH1[tIdx], sh = M.sH1[tIdx], mw = M.mW1[tid], sw = M.sW1[tid];
            const float mm = fmaxf(mh, mw);
            const float eh = __expf(mh - mm), ew = __expf(mw - mm);
            const float inv = 1.f / (sh * eh + sw * ew);
            M.fH1[tid] = eh * inv; M.fW1[tid] = ew * inv;
        }
        {
            const float mh = M.mH2[tIdx], sh = M.sH2[tIdx], mw = M.mW2[tid], sw = M.sW2[tid];
            const float mm = fmaxf(mh, mw);
            const float eh = __expf(mh - mm), ew = __expf(mw - mm);
            const float inv = 1.f / (sh * eh + sw * ew);
            M.fH2[tid] = eh * inv; M.fW2[tid] = ew * inv;
        }
    }
}

// ---------- K4: combine att + residuals, write s1/s2 (bf16), reduce stats ----------
__global__ __launch_bounds__(256) void combine_reduce(
    const bf16t* __restrict__ oH1, const bf16t* __restrict__ oW1,
    const bf16t* __restrict__ oH2, const bf16t* __restrict__ oW2,
    const float* __restrict__ fH1, const float* __restrict__ fW1,
    const float* __restrict__ fH2, const float* __restrict__ fW2,
    const float* __restrict__ x1, const float* __restrict__ x2,
    const float* __restrict__ gamma1, const float* __restrict__ gamma2,
    bf16t* __restrict__ s1, bf16t* __restrict__ s2,
    float* __restrict__ accum, unsigned* __restrict__ accmax)
{
    const int t = threadIdx.x, chunk = blockIdx.x, c = blockIdx.y, b = blockIdx.z;
    const float g1v = gamma1[0], g2v = gamma2[0];
    const size_t cb = ((size_t)(b * 64 + c)) * HW;
    const size_t pb = (size_t)b * HW;

    float pS1 = 0, pSS1 = 0, pSX1 = 0, pX1 = 0, pXX1 = 0, pM1 = -3e38f;
    float pS2 = 0, pSS2 = 0, pSX2 = 0, pX2 = 0, pXX2 = 0, pM2 = -3e38f;

    for (int i = 0; i < 16; i++) {
        const int pidx = chunk * 4096 + i * 256 + t;
        const float f_h1 = fH1[pb + pidx], f_w1 = fW1[pb + pidx];
        const float f_h2 = fH2[pb + pidx], f_w2 = fW2[pb + pidx];
        const float a1 = bf2f(oH1[cb + pidx]) * f_h1 + bf2f(oW1[cb + pidx]) * f_w1;
        const float a2 = bf2f(oH2[cb + pidx]) * f_h2 + bf2f(oW2[cb + pidx]) * f_w2;
        const float x1v = x1[cb + pidx], x2v = x2[cb + pidx];
        const float s1v = g2v * a2 + x2v + x1v;
        const float s2v = g1v * a1 + x1v + x2v;
        s1[cb + pidx] = f2bf(s1v);
        s2[cb + pidx] = f2bf(s2v);
        pS1 += s1v; pSS1 += s1v * s1v; pSX1 += s1v * x1v; pX1 += x1v; pXX1 += x1v * x1v; pM1 = fmaxf(pM1, s1v);
        pS2 += s2v; pSS2 += s2v * s2v; pSX2 += s2v * x2v; pX2 += x2v; pXX2 += x2v * x2v; pM2 = fmaxf(pM2, s2v);
    }

    __shared__ float wred[12][4];
    float vals[12] = {pS1, pSS1, pSX1, pX1, pXX1, pM1, pS2, pSS2, pSX2, pX2, pXX2, pM2};
    const int lane = t & 63, wave = t >> 6;
#pragma unroll
    for (int iv = 0; iv < 12; iv++) {
        float v = vals[iv];
        const bool isMax = (iv == 5 || iv == 11);
#pragma unroll
        for (int off = 32; off > 0; off >>= 1) {
            const float o = __shfl_down(v, off, 64);
            v = isMax ? fmaxf(v, o) : (v + o);
        }
        if (lane == 0) wred[iv][wave] = v;
    }
    __syncthreads();
    if (t < 12) {
        const bool isMax = (t == 5 || t == 11);
        float v = wred[t][0];
        for (int i = 1; i < 4; i++) v = isMax ? fmaxf(v, wred[t][i]) : (v + wred[t][i]);
        const int stream = (t >= 6) ? 1 : 0;
        const int kk = t - stream * 6;
        if (kk == 5) atomicMax(&accmax[(stream * 2 + b) * 64 + c], fenc(v));
        else atomicAdd(&accum[((stream * 2 + b) * 64 + c) * 5 + kk], v);
    }
}

// ---------- K5: gates (shareca MLP) + analytic BN coefficients ----------
__global__ __launch_bounds__(256) void gates_bn(
    const float* __restrict__ accum, const unsigned* __restrict__ accmax,
    const float* __restrict__ sc1_w1, const float* __restrict__ sc1_b1,
    const float* __restrict__ sc1_w2, const float* __restrict__ sc1_b2,
    const float* __restrict__ sc2_w1, const float* __restrict__ sc2_b1,
    const float* __restrict__ sc2_w2, const float* __restrict__ sc2_b2,
    const float* __restrict__ bn1_scale, const float* __restrict__ bn1_bias,
    const float* __restrict__ bn2_scale, const float* __restrict__ bn2_bias,
    float* __restrict__ gates, float* __restrict__ AB)
{
    const int t = threadIdx.x;
    const int stream = t >> 7, b = (t >> 6) & 1, c = t & 63;
    __shared__ float meanS[256], maxS[256], e1S[256], e2S[256];

    const float S = accum[t * 5 + 0], SS = accum[t * 5 + 1], SX = accum[t * 5 + 2];
    const float X = accum[t * 5 + 3], XX = accum[t * 5 + 4];
    meanS[t] = S * (1.f / 65536.f);
    maxS[t] = fdec(accmax[t]);
    __syncthreads();

    const float* w1 = stream ? sc2_w1 : sc1_w1;
    const float* b1 = stream ? sc2_b1 : sc1_b1;
    const float* w2 = stream ? sc2_w2 : sc1_w2;
    const float* b2 = stream ? sc2_b2 : sc1_b2;
    float om = b2[c], ox = b2[c];
    const int base = stream * 128 + b * 64;
#pragma unroll
    for (int r = 0; r < 4; r++) {
        float hm = b1[r], hx = b1[r];
        for (int cc = 0; cc < 64; cc++) {
            hm += w1[r * 64 + cc] * meanS[base + cc];
            hx += w1[r * 64 + cc] * maxS[base + cc];
        }
        hm = fmaxf(hm, 0.f); hx = fmaxf(hx, 0.f);
        om += w2[c * 4 + r] * hm;
        ox += w2[c * 4 + r] * hx;
    }
    const float gate = 1.f / (1.f + __expf(-(om + ox)));
    gates[t] = gate;
    e1S[t] = gate * S + X;
    e2S[t] = gate * gate * SS + 2.f * gate * SX + XX;
    __syncthreads();
    if (b == 0) {
        const float sumY = e1S[t] + e1S[t + 64];
        const float sumY2 = e2S[t] + e2S[t + 64];
        const float meanY = sumY * (1.f / 131072.f);
        const float varY = sumY2 * (1.f / 131072.f) - meanY * meanY;
        const float sc = stream ? bn2_scale[c] : bn1_scale[c];
        const float bi = stream ? bn2_bias[c] : bn1_bias[c];
        const float A = sc * rsqrtf(varY + 1e-5f);
        AB[stream * 128 + c] = A;
        AB[stream * 128 + 64 + c] = bi - meanY * A;
    }
}

// ---------- K6: final elementwise ----------
__global__ __launch_bounds__(256) void finalize(
    const bf16t* __restrict__ s1, const bf16t* __restrict__ s2,
    const float* __restrict__ x1, const float* __restrict__ x2,
    const float* __restrict__ gates, const float* __restrict__ AB,
    float* __restrict__ out)
{
    const size_t tid = (size_t)blockIdx.x * 256 + threadIdx.x;
    const size_t idx = tid * 4;
    const int b = (int)(idx >> 22);
    const int c = (int)((idx >> 16) & 63);
    const bool odd = (c & 1) != 0;
    const float g1 = gates[b * 64 + c], g2 = gates[128 + b * 64 + c];
    const float A1 = AB[c], B1 = AB[64 + c], A2 = AB[128 + c], B2 = AB[192 + c];

    const uint2 su1 = *(const uint2*)(s1 + idx);
    const uint2 su2 = *(const uint2*)(s2 + idx);
    const float4 x1v = *(const float4*)(x1 + idx);
    const float4 x2v = *(const float4*)(x2 + idx);
    float s1f[4] = {bflo(su1.x), bfhi(su1.x), bflo(su1.y), bfhi(su1.y)};
    float s2f[4] = {bflo(su2.x), bfhi(su2.x), bflo(su2.y), bfhi(su2.y)};
    float xa[4] = {x1v.x, x1v.y, x1v.z, x1v.w};
    float xb[4] = {x2v.x, x2v.y, x2v.z, x2v.w};
    float o1[4], o2[4];
#pragma unroll
    for (int j = 0; j < 4; j++) {
        const float y1 = g1 * s1f[j] + xa[j];
        const float y2 = g2 * s2f[j] + xb[j];
        o1[j] = odd ? fmaxf(A1 * y1 + B1, 0.f) : xa[j];
        o2[j] = odd ? fmaxf(A2 * y2 + B2, 0.f) : xb[j];
    }
    *(float4*)(out + idx) = make_float4(o1[0], o1[1], o1[2], o1[3]);
    *(float4*)(out + 8388608 + idx) = make_float4(o2[0], o2[1], o2[2], o2[3]);
}

// ---------- host ----------
extern "C" void kernel_launch(void* const* d_in, const int* in_sizes, int n_in,
                              void* d_out, int out_size, void* d_ws, size_t ws_size,
                              hipStream_t stream) {
    (void)in_sizes; (void)n_in; (void)out_size; (void)ws_size;
    const float* x1 = (const float*)d_in[0];
    const float* x2 = (const float*)d_in[1];
    const float* wq1 = (const float*)d_in[2];  const float* bq1 = (const float*)d_in[3];
    const float* wq2 = (const float*)d_in[4];  const float* bq2 = (const float*)d_in[5];
    const float* wk1 = (const float*)d_in[6];  const float* bk1 = (const float*)d_in[7];
    const float* wk2 = (const float*)d_in[8];  const float* bk2 = (const float*)d_in[9];
    const float* wv1 = (const float*)d_in[10]; const float* bv1 = (const float*)d_in[11];
    const float* wv2 = (const float*)d_in[12]; const float* bv2 = (const float*)d_in[13];
    const float* gamma1 = (const float*)d_in[14];
    const float* gamma2 = (const float*)d_in[15];
    const float* sc1_w1 = (const float*)d_in[16]; const float* sc1_b1 = (const float*)d_in[17];
    const float* sc1_w2 = (const float*)d_in[18]; const float* sc1_b2 = (const float*)d_in[19];
    const float* sc2_w1 = (const float*)d_in[20]; const float* sc2_b1 = (const float*)d_in[21];
    const float* sc2_w2 = (const float*)d_in[22]; const float* sc2_b2 = (const float*)d_in[23];
    const float* bn1_scale = (const float*)d_in[24]; const float* bn1_bias = (const float*)d_in[25];
    const float* bn2_scale = (const float*)d_in[26]; const float* bn2_bias = (const float*)d_in[27];

    char* p = (char*)d_ws;
    const size_t SZ_QK = 2097152;   // bf16 (B,8,H,W)
    const size_t SZ_V = 16777216;   // bf16 (B,64,H,W)
    const size_t SZ_ST = 524288;    // fp32 (B,H,W)

    // contiguous input block for single-transpose dispatch: q1,k1,q2,k2,v1,v2
    bf16t* q1 = (bf16t*)(p + 0 * SZ_QK);
    bf16t* k1 = (bf16t*)(p + 1 * SZ_QK);
    bf16t* q2 = (bf16t*)(p + 2 * SZ_QK);
    bf16t* k2 = (bf16t*)(p + 3 * SZ_QK);
    bf16t* v1 = (bf16t*)(p + 4 * SZ_QK);
    bf16t* v2 = (bf16t*)(p + 4 * SZ_QK + SZ_V);
    size_t off = 4 * SZ_QK + 2 * SZ_V;            // 41,943,040
    bf16t* q1T = (bf16t*)(p + off + 0 * SZ_QK);
    bf16t* k1T = (bf16t*)(p + off + 1 * SZ_QK);
    bf16t* q2T = (bf16t*)(p + off + 2 * SZ_QK);
    bf16t* k2T = (bf16t*)(p + off + 3 * SZ_QK);
    bf16t* v1T = (bf16t*)(p + off + 4 * SZ_QK);
    bf16t* v2T = (bf16t*)(p + off + 4 * SZ_QK + SZ_V);
    off += 4 * SZ_QK + 2 * SZ_V;                  // 83,886,080
    bf16t* oH1T = (bf16t*)(p + off); off += SZ_V;
    bf16t* oH2T = (bf16t*)(p + off); off += SZ_V;
    bf16t* oW1 = (bf16t*)(p + off); off += SZ_V;
    bf16t* oW2 = (bf16t*)(p + off); off += SZ_V;
    float* mH1T = (float*)(p + off); off += SZ_ST;
    float* sH1T = (float*)(p + off); off += SZ_ST;
    float* mH2T = (float*)(p + off); off += SZ_ST;
    float* sH2T = (float*)(p + off); off += SZ_ST;
    float* mW1 = (float*)(p + off); off += SZ_ST;
    float* sW1 = (float*)(p + off); off += SZ_ST;
    float* mW2 = (float*)(p + off); off += SZ_ST;
    float* sW2 = (float*)(p + off); off += SZ_ST;
    float* fH1 = (float*)(p + off); off += SZ_ST;
    float* fW1 = (float*)(p + off); off += SZ_ST;
    float* fH2 = (float*)(p + off); off += SZ_ST;
    float* fW2 = (float*)(p + off); off += SZ_ST;
    float* accum = (float*)(p + off);                  // 1280 f32
    unsigned* accmax = (unsigned*)(p + off + 5120);    // 256 u32
    float* gates = (float*)(p + off + 6144);
    float* AB = (float*)(p + off + 7168);

    // overlays (stream-ordered producers precede the overwrite):
    bf16t* oH1 = v1T;   // v1T,v2T dead after rowcc
    bf16t* oH2 = v2T;
    bf16t* s1 = oH1T;   // oH1T,oH2T dead after transpose_merge
    bf16t* s2 = oH2T;

    // K1: fused convs
    ConvArgs CA;
    CA.x[0] = x1; CA.x[1] = x2;
    CA.wq[0] = wq1; CA.wq[1] = wq2; CA.bq[0] = bq1; CA.bq[1] = bq2;
    CA.wk[0] = wk1; CA.wk[1] = wk2; CA.bk[0] = bk1; CA.bk[1] = bk2;
    CA.wv[0] = wv1; CA.wv[1] = wv2; CA.bv[0] = bv1; CA.bv[1] = bv2;
    CA.q[0] = q1; CA.q[1] = q2; CA.k[0] = k1; CA.k[1] = k2;
    CA.v[0] = v1; CA.v[1] = v2;
    conv_qkv<<<dim3(4, 64, 4), 256, 0, stream>>>(CA);

    // K2: all input transposes in one dispatch (q1..k2 = 64 slices, v1,v2 = 256)
    transpose16<<<dim3(4, 4, 320), 256, 0, stream>>>(q1, q1T);

    // K3: fused criss-cross
    RowccArgs RA;
    RA.q[0] = q2T; RA.k[0] = k1T; RA.v[0] = v1T; RA.o[0] = oH1T; RA.mo[0] = mH1T; RA.so[0] = sH1T;
    RA.q[1] = q1T; RA.k[1] = k2T; RA.v[1] = v2T; RA.o[1] = oH2T; RA.mo[1] = mH2T; RA.so[1] = sH2T;
    RA.q[2] = q2;  RA.k[2] = k1;  RA.v[2] = v1;  RA.o[2] = oW1;  RA.mo[2] = mW1;  RA.so[2] = sW1;
    RA.q[3] = q1;  RA.k[3] = k2;  RA.v[3] = v2;  RA.o[3] = oW2;  RA.mo[3] = mW2;  RA.so[3] = sW2;
    rowcc_mfma<<<dim3(256, 2, 4), 256, 0, stream>>>(RA);

    // K4: output transpose (oH1T,oH2T -> oH1,oH2) + merge factors + accum zeroing
    TMArgs TM;
    TM.tin = oH1T; TM.tout = oH1;
    TM.mH1 = mH1T; TM.sH1 = sH1T; TM.mW1 = mW1; TM.sW1 = sW1;
    TM.mH2 = mH2T; TM.sH2 = sH2T; TM.mW2 = mW2; TM.sW2 = sW2;
    TM.fH1 = fH1; TM.fW1 = fW1; TM.fH2 = fH2; TM.fW2 = fW2;
    TM.zeroRegion = (unsigned*)accum;
    transpose_merge<<<dim3(4, 4, 272), 256, 0, stream>>>(TM);

    combine_reduce<<<dim3(16, 64, 2), 256, 0, stream>>>(
        oH1, oW1, oH2, oW2, fH1, fW1, fH2, fW2, x1, x2, gamma1, gamma2,
        s1, s2, accum, accmax);

    gates_bn<<<1, 256, 0, stream>>>(accum, accmax,
                                    sc1_w1, sc1_b1, sc1_w2, sc1_b2,
                                    sc2_w1, sc2_b1, sc2_w2, sc2_b2,
                                    bn1_scale, bn1_bias, bn2_scale, bn2_bias,
                                    gates, AB);

    finalize<<<8192, 256, 0, stream>>>(s1, s2, x1, x2, gates, AB, (float*)d_out);
}

// Round 4
// 366.513 us; speedup vs baseline: 1.8309x; 1.0772x over previous
//
#include <hip/hip_runtime.h>
#include <hip/hip_bf16.h>
#include <cstdint>
#include <cstddef>

typedef unsigned short bf16t;
typedef __attribute__((ext_vector_type(8))) short bf16x8;  // 8 bf16 (4 VGPRs)
typedef __attribute__((ext_vector_type(4))) float f32x4;   // MFMA C/D

// ---------- helpers ----------
__device__ __forceinline__ unsigned short f2bf(float f) {
    unsigned u = __float_as_uint(f);
    u += 0x7fffu + ((u >> 16) & 1u);   // RNE
    return (unsigned short)(u >> 16);
}
__device__ __forceinline__ float bf2f(unsigned short h) {
    return __uint_as_float(((unsigned)h) << 16);
}
__device__ __forceinline__ float bflo(unsigned u) { return __uint_as_float(u << 16); }
__device__ __forceinline__ float bfhi(unsigned u) { return __uint_as_float(u & 0xffff0000u); }
// packed f32x2 -> bf16x2 via v_cvt_pk_bf16_f32
__device__ __forceinline__ unsigned pk2(float a, float b) {
    __hip_bfloat162 h = __float22bfloat162_rn(make_float2(a, b));
    return *(unsigned*)&h;
}

// order-preserving float<->uint encoding for atomicMax
__device__ __forceinline__ unsigned fenc(float f) {
    unsigned u = __float_as_uint(f);
    return (u & 0x80000000u) ? ~u : (u | 0x80000000u);
}
__device__ __forceinline__ float fdec(unsigned u) {
    return __uint_as_float((u & 0x80000000u) ? (u ^ 0x80000000u) : ~u);
}

#define HW 65536

// ---------- K1: fused 1x1 conv for both streams (q,k,v bf16) + accum zeroing ----------
struct ConvArgs {
    const float* x[2];
    const float* wq[2]; const float* bq[2];
    const float* wk[2]; const float* bk[2];
    const float* wv[2]; const float* bv[2];
    bf16t* q[2]; bf16t* k[2]; bf16t* v[2];
    unsigned* zeroR;    // 1536 u32: accum (1280 f32) + accmax (256 u32)
};

__global__ __launch_bounds__(256) void conv_qkv(ConvArgs A)
{
    const int t = threadIdx.x;
    const int z = blockIdx.z;
    const int s = z >> 1, b = z & 1;
    if (z == 0 && blockIdx.x == 0 && blockIdx.y == 0) {
#pragma unroll
        for (int i = 0; i < 6; i++) A.zeroR[t + i * 256] = 0u;
    }
    const int h = blockIdx.y * 4 + (t >> 6);
    const int w = blockIdx.x * 64 + (t & 63);
    const int pix = h * 256 + w;

    const float* wq = A.wq[s]; const float* wk = A.wk[s]; const float* wv = A.wv[s];
    float qa[8], ka[8], va[64];
#pragma unroll
    for (int o = 0; o < 8; o++) { qa[o] = A.bq[s][o]; ka[o] = A.bk[s][o]; }
#pragma unroll
    for (int o = 0; o < 64; o++) va[o] = A.bv[s][o];

    const float* xb = A.x[s] + (size_t)b * 64 * HW + pix;
    for (int c = 0; c < 64; c++) {
        const float xv = xb[(size_t)c * HW];
#pragma unroll
        for (int o = 0; o < 8; o++) { qa[o] += wq[o * 64 + c] * xv; ka[o] += wk[o * 64 + c] * xv; }
#pragma unroll
        for (int o = 0; o < 64; o++) va[o] += wv[o * 64 + c] * xv;
    }
    bf16t* qo = A.q[s] + (size_t)b * 8 * HW + pix;
    bf16t* ko = A.k[s] + (size_t)b * 8 * HW + pix;
    bf16t* vo = A.v[s] + (size_t)b * 64 * HW + pix;
#pragma unroll
    for (int o = 0; o < 8; o++) { qo[(size_t)o * HW] = f2bf(qa[o]); ko[(size_t)o * HW] = f2bf(ka[o]); }
#pragma unroll
    for (int o = 0; o < 64; o++) vo[(size_t)o * HW] = f2bf(va[o]);
}

// ---------- bf16 transpose: per-slice 256x256, 64x64 tiles, z = slice ----------
__global__ __launch_bounds__(256) void transpose16(const bf16t* __restrict__ in, bf16t* __restrict__ out)
{
    __shared__ bf16t tile[64][68];
    const size_t zo = (size_t)blockIdx.z * HW;
    const int i0 = blockIdx.y * 64, j0 = blockIdx.x * 64;
    const int lc = threadIdx.x & 63, rg = threadIdx.x >> 6;
#pragma unroll
    for (int rr = 0; rr < 16; rr++) {
        int row = rg * 16 + rr;
        tile[row][lc] = in[zo + (size_t)(i0 + row) * 256 + j0 + lc];
    }
    __syncthreads();
#pragma unroll
    for (int rr = 0; rr < 16; rr++) {
        int row = rg * 16 + rr;
        out[zo + (size_t)(j0 + row) * 256 + i0 + lc] = tile[lc][row];
    }
}

// ---------- K2: criss-cross rows, all 4 variants, MFMA scores + MFMA PV ----------
// No max-subtraction (scores bounded ~|8|): p = exp(e) directly; denominator
// s = sum(p) accumulated in-thread, reduced once at the end. Column-pass
// variants (z<2) scatter s into row-frame so combine reads coalesced.
struct RowccArgs {
    const bf16t* q[4]; const bf16t* k[4]; const bf16t* v[4];
    bf16t* o[4]; float* so[4];
};

__global__ __launch_bounds__(256, 3) void rowcc_mfma(RowccArgs P)
{
    // LDS: vs[64][264] bf16 (33792) | ps[256][40] bf16 (20480) = 54272 -> 3 blocks/CU
    __shared__ __align__(16) char smem[54272];
    bf16t* vs = (bf16t*)smem;
    bf16t* ps = (bf16t*)(smem + 33792);

    const int t = threadIdx.x;
    const int r = blockIdx.x, b = blockIdx.y, z = blockIdx.z;
    const bool mask = (z < 2);
    const int lane = t & 63, wv = t >> 6, quad = lane >> 4, l16 = lane & 15;
    const int wband = wv * 64;

    const bf16t* qp = P.q[z];
    const bf16t* kp = P.k[z];
    const bf16t* vp = P.v[z];

    // --- stage V as [c][j] (row stride 264) ---
    const size_t vb = (size_t)b * 64 * HW + (size_t)r * 256;
#pragma unroll
    for (int i = 0; i < 8; i++) {
        const int qd = i * 256 + t;
        const int c = qd >> 5, jc = (qd & 31) * 8;
        *(uint4*)&vs[c * 264 + jc] = *(const uint4*)&vp[vb + (size_t)c * HW + jc];
    }

    // --- Q B-frags from global (quad0 lanes only; quads 1-3 are K-zero-pad) ---
    const bf16x8 zfr = {0, 0, 0, 0, 0, 0, 0, 0};
    bf16x8 qfr[4] = {zfr, zfr, zfr, zfr};
    const size_t rowb = (size_t)b * 8 * HW + (size_t)r * 256;
    if (quad == 0) {
#pragma unroll
        for (int wt = 0; wt < 4; wt++) {
            const int w_g = wband + wt * 16 + l16;
#pragma unroll
            for (int ch = 0; ch < 8; ch++)
                qfr[wt][ch] = (short)qp[rowb + (size_t)ch * HW + w_g];
        }
    }

    const f32x4 z4 = {0.f, 0.f, 0.f, 0.f};
    f32x4 acc[4][4];
#pragma unroll
    for (int i = 0; i < 4; i++)
#pragma unroll
        for (int j = 0; j < 4; j++) acc[i][j] = z4;
    float s_t[4] = {0.f, 0.f, 0.f, 0.f};

    // K A-frag prefetch for jt=0
    bf16x8 kcur[2] = {zfr, zfr};
    if (quad == 0) {
#pragma unroll
        for (int jtile = 0; jtile < 2; jtile++)
#pragma unroll
            for (int ch = 0; ch < 8; ch++)
                kcur[jtile][ch] = (short)kp[rowb + (size_t)ch * HW + jtile * 16 + l16];
    }

    __syncthreads();

    for (int jt = 0; jt < 8; jt++) {
        const int j0 = jt * 32;
        // scores: E[m=j][n=w]; lane: col w=l16, rows j=quad*4+reg
        f32x4 e[4][2];
#pragma unroll
        for (int wt = 0; wt < 4; wt++)
#pragma unroll
            for (int jtile = 0; jtile < 2; jtile++)
                e[wt][jtile] = __builtin_amdgcn_mfma_f32_16x16x32_bf16(kcur[jtile], qfr[wt], z4, 0, 0, 0);

        // prefetch next jt's K frags (overlaps with exp/PV below)
        bf16x8 knext[2] = {zfr, zfr};
        if (jt < 7 && quad == 0) {
            const int jn = (jt + 1) * 32;
#pragma unroll
            for (int jtile = 0; jtile < 2; jtile++)
#pragma unroll
                for (int ch = 0; ch < 8; ch++)
                    knext[jtile][ch] = (short)kp[rowb + (size_t)ch * HW + jn + jtile * 16 + l16];
        }

        // diagonal mask (only 2 of 8 jt can contain this wave's diagonal)
        if (mask && (jt >> 1) == wv) {
#pragma unroll
            for (int wt = 0; wt < 4; wt++) {
                const int w_g = wband + wt * 16 + l16;
#pragma unroll
                for (int jtile = 0; jtile < 2; jtile++)
#pragma unroll
                    for (int rr = 0; rr < 4; rr++)
                        if (j0 + jtile * 16 + quad * 4 + rr == w_g) e[wt][jtile][rr] = -3.0e38f;
            }
        }

        // p = exp(e); accumulate denominator; write P to LDS in A-layout
#pragma unroll
        for (int wt = 0; wt < 4; wt++) {
#pragma unroll
            for (int jtile = 0; jtile < 2; jtile++) {
                const float p0 = __expf(e[wt][jtile][0]);
                const float p1 = __expf(e[wt][jtile][1]);
                const float p2 = __expf(e[wt][jtile][2]);
                const float p3 = __expf(e[wt][jtile][3]);
                s_t[wt] += (p0 + p1) + (p2 + p3);
                uint2 u; u.x = pk2(p0, p1); u.y = pk2(p2, p3);
                *(uint2*)&ps[(wband + wt * 16 + l16) * 40 + jtile * 16 + quad * 4] = u;
            }
        }

        // PV: A = P (w x j), B = V (j x c)
        bf16x8 afr[4], bfr[4];
#pragma unroll
        for (int wt = 0; wt < 4; wt++)
            afr[wt] = *(const bf16x8*)&ps[(wband + wt * 16 + l16) * 40 + quad * 8];
#pragma unroll
        for (int ct = 0; ct < 4; ct++)
            bfr[ct] = *(const bf16x8*)&vs[(ct * 16 + l16) * 264 + j0 + quad * 8];
#pragma unroll
        for (int wt = 0; wt < 4; wt++)
#pragma unroll
            for (int ct = 0; ct < 4; ct++)
                acc[wt][ct] = __builtin_amdgcn_mfma_f32_16x16x32_bf16(afr[wt], bfr[ct], acc[wt][ct], 0, 0, 0);

        kcur[0] = knext[0]; kcur[1] = knext[1];
    }

    // denominator: reduce across quads (each quad holds a disjoint j-subset)
#pragma unroll
    for (int wt = 0; wt < 4; wt++) {
        float s = s_t[wt];
        s += __shfl_xor(s, 16, 64);
        s += __shfl_xor(s, 32, 64);
        s_t[wt] = s;
    }
    if (quad == 0) {
#pragma unroll
        for (int wt = 0; wt < 4; wt++) {
            const int w_g = wband + wt * 16 + l16;
            if (mask)  // column pass: pixel (h=w_g, w=r) in row-frame
                P.so[z][(size_t)b * HW + w_g * 256 + r] = s_t[wt];
            else
                P.so[z][(size_t)b * HW + r * 256 + w_g] = s_t[wt];
        }
    }

    // epilogue: C-layout -> LDS [c][w] -> coalesced global [c][w]
    __syncthreads();
    bf16t* o_lds = (bf16t*)smem;   // [64][264], overlays vs
#pragma unroll
    for (int wt = 0; wt < 4; wt++) {
        const int w0 = wband + wt * 16 + quad * 4;
#pragma unroll
        for (int ct = 0; ct < 4; ct++) {
            const int c = ct * 16 + l16;
            uint2 u;
            u.x = pk2(acc[wt][ct][0], acc[wt][ct][1]);
            u.y = pk2(acc[wt][ct][2], acc[wt][ct][3]);
            *(uint2*)&o_lds[c * 264 + w0] = u;
        }
    }
    __syncthreads();
    bf16t* ob = P.o[z] + (size_t)b * 64 * HW + (size_t)r * 256;
#pragma unroll
    for (int i = 0; i < 8; i++) {
        const int qd = i * 256 + t;
        const int c = qd >> 5, w8 = (qd & 31) * 8;
        *(uint4*)&ob[(size_t)c * HW + w8] = *(const uint4*)&o_lds[c * 264 + w8];
    }
}

// ---------- K4: combine att + residuals, write s1/s2 (bf16), reduce stats ----------
__global__ __launch_bounds__(256) void combine_reduce(
    const bf16t* __restrict__ oH1, const bf16t* __restrict__ oW1,
    const bf16t* __restrict__ oH2, const bf16t* __restrict__ oW2,
    const float* __restrict__ sH1, const float* __restrict__ sW1,
    const float* __restrict__ sH2, const float* __restrict__ sW2,
    const float* __restrict__ x1, const float* __restrict__ x2,
    const float* __restrict__ gamma1, const float* __restrict__ gamma2,
    bf16t* __restrict__ s1, bf16t* __restrict__ s2,
    float* __restrict__ accum, unsigned* __restrict__ accmax)
{
    const int t = threadIdx.x, chunk = blockIdx.x, c = blockIdx.y, b = blockIdx.z;
    const float g1v = gamma1[0], g2v = gamma2[0];
    const size_t cb = ((size_t)(b * 64 + c)) * HW;
    const size_t pb = (size_t)b * HW;

    float pS1 = 0, pSS1 = 0, pSX1 = 0, pX1 = 0, pXX1 = 0, pM1 = -3e38f;
    float pS2 = 0, pSS2 = 0, pSX2 = 0, pX2 = 0, pXX2 = 0, pM2 = -3e38f;

    for (int i = 0; i < 16; i++) {
        const int pidx = chunk * 4096 + i * 256 + t;
        const float inv1 = 1.f / (sH1[pb + pidx] + sW1[pb + pidx]);
        const float inv2 = 1.f / (sH2[pb + pidx] + sW2[pb + pidx]);
        const float a1 = (bf2f(oH1[cb + pidx]) + bf2f(oW1[cb + pidx])) * inv1;
        const float a2 = (bf2f(oH2[cb + pidx]) + bf2f(oW2[cb + pidx])) * inv2;
        const float x1v = x1[cb + pidx], x2v = x2[cb + pidx];
        const float s1v = g2v * a2 + x2v + x1v;
        const float s2v = g1v * a1 + x1v + x2v;
        s1[cb + pidx] = f2bf(s1v);
        s2[cb + pidx] = f2bf(s2v);
        pS1 += s1v; pSS1 += s1v * s1v; pSX1 += s1v * x1v; pX1 += x1v; pXX1 += x1v * x1v; pM1 = fmaxf(pM1, s1v);
        pS2 += s2v; pSS2 += s2v * s2v; pSX2 += s2v * x2v; pX2 += x2v; pXX2 += x2v * x2v; pM2 = fmaxf(pM2, s2v);
    }

    __shared__ float wred[12][4];
    float vals[12] = {pS1, pSS1, pSX1, pX1, pXX1, pM1, pS2, pSS2, pSX2, pX2, pXX2, pM2};
    const int lane = t & 63, wave = t >> 6;
#pragma unroll
    for (int iv = 0; iv < 12; iv++) {
        float v = vals[iv];
        const bool isMax = (iv == 5 || iv == 11);
#pragma unroll
        for (int off = 32; off > 0; off >>= 1) {
            const float o = __shfl_down(v, off, 64);
            v = isMax ? fmaxf(v, o) : (v + o);
        }
        if (lane == 0) wred[iv][wave] = v;
    }
    __syncthreads();
    if (t < 12) {
        const bool isMax = (t == 5 || t == 11);
        float v = wred[t][0];
        for (int i = 1; i < 4; i++) v = isMax ? fmaxf(v, wred[t][i]) : (v + wred[t][i]);
        const int stream = (t >= 6) ? 1 : 0;
        const int kk = t - stream * 6;
        if (kk == 5) atomicMax(&accmax[(stream * 2 + b) * 64 + c], fenc(v));
        else atomicAdd(&accum[((stream * 2 + b) * 64 + c) * 5 + kk], v);
    }
}

// ---------- K5: gates (shareca MLP) + analytic BN coefficients ----------
__global__ __launch_bounds__(256) void gates_bn(
    const float* __restrict__ accum, const unsigned* __restrict__ accmax,
    const float* __restrict__ sc1_w1, const float* __restrict__ sc1_b1,
    const float* __restrict__ sc1_w2, const float* __restrict__ sc1_b2,
    const float* __restrict__ sc2_w1, const float* __restrict__ sc2_b1,
    const float* __restrict__ sc2_w2, const float* __restrict__ sc2_b2,
    const float* __restrict__ bn1_scale, const float* __restrict__ bn1_bias,
    const float* __restrict__ bn2_scale, const float* __restrict__ bn2_bias,
    float* __restrict__ gates, float* __restrict__ AB)
{
    const int t = threadIdx.x;
    const int stream = t >> 7, b = (t >> 6) & 1, c = t & 63;
    __shared__ float meanS[256], maxS[256], e1S[256], e2S[256];

    const float S = accum[t * 5 + 0], SS = accum[t * 5 + 1], SX = accum[t * 5 + 2];
    const float X = accum[t * 5 + 3], XX = accum[t * 5 + 4];
    meanS[t] = S * (1.f / 65536.f);
    maxS[t] = fdec(accmax[t]);
    __syncthreads();

    const float* w1 = stream ? sc2_w1 : sc1_w1;
    const float* b1 = stream ? sc2_b1 : sc1_b1;
    const float* w2 = stream ? sc2_w2 : sc1_w2;
    const float* b2 = stream ? sc2_b2 : sc1_b2;
    float om = b2[c], ox = b2[c];
    const int base = stream * 128 + b * 64;
#pragma unroll
    for (int r = 0; r < 4; r++) {
        float hm = b1[r], hx = b1[r];
        for (int cc = 0; cc < 64; cc++) {
            hm += w1[r * 64 + cc] * meanS[base + cc];
            hx += w1[r * 64 + cc] * maxS[base + cc];
        }
        hm = fmaxf(hm, 0.f); hx = fmaxf(hx, 0.f);
        om += w2[c * 4 + r] * hm;
        ox += w2[c * 4 + r] * hx;
    }
    const float gate = 1.f / (1.f + __expf(-(om + ox)));
    gates[t] = gate;
    e1S[t] = gate * S + X;
    e2S[t] = gate * gate * SS + 2.f * gate * SX + XX;
    __syncthreads();
    if (b == 0) {
        const float sumY = e1S[t] + e1S[t + 64];
        const float sumY2 = e2S[t] + e2S[t + 64];
        const float meanY = sumY * (1.f / 131072.f);
        const float varY = sumY2 * (1.f / 131072.f) - meanY * meanY;
        const float sc = stream ? bn2_scale[c] : bn1_scale[c];
        const float bi = stream ? bn2_bias[c] : bn1_bias[c];
        const float A = sc * rsqrtf(varY + 1e-5f);
        AB[stream * 128 + c] = A;
        AB[stream * 128 + 64 + c] = bi - meanY * A;
    }
}

// ---------- K6: final elementwise ----------
__global__ __launch_bounds__(256) void finalize(
    const bf16t* __restrict__ s1, const bf16t* __restrict__ s2,
    const float* __restrict__ x1, const float* __restrict__ x2,
    const float* __restrict__ gates, const float* __restrict__ AB,
    float* __restrict__ out)
{
    const size_t tid = (size_t)blockIdx.x * 256 + threadIdx.x;
    const size_t idx = tid * 4;
    const int b = (int)(idx >> 22);
    const int c = (int)((idx >> 16) & 63);
    const bool odd = (c & 1) != 0;
    const float g1 = gates[b * 64 + c], g2 = gates[128 + b * 64 + c];
    const float A1 = AB[c], B1 = AB[64 + c], A2 = AB[128 + c], B2 = AB[192 + c];

    const uint2 su1 = *(const uint2*)(s1 + idx);
    const uint2 su2 = *(const uint2*)(s2 + idx);
    const float4 x1v = *(const float4*)(x1 + idx);
    const float4 x2v = *(const float4*)(x2 + idx);
    float s1f[4] = {bflo(su1.x), bfhi(su1.x), bflo(su1.y), bfhi(su1.y)};
    float s2f[4] = {bflo(su2.x), bfhi(su2.x), bflo(su2.y), bfhi(su2.y)};
    float xa[4] = {x1v.x, x1v.y, x1v.z, x1v.w};
    float xb[4] = {x2v.x, x2v.y, x2v.z, x2v.w};
    float o1[4], o2[4];
#pragma unroll
    for (int j = 0; j < 4; j++) {
        const float y1 = g1 * s1f[j] + xa[j];
        const float y2 = g2 * s2f[j] + xb[j];
        o1[j] = odd ? fmaxf(A1 * y1 + B1, 0.f) : xa[j];
        o2[j] = odd ? fmaxf(A2 * y2 + B2, 0.f) : xb[j];
    }
    *(float4*)(out + idx) = make_float4(o1[0], o1[1], o1[2], o1[3]);
    *(float4*)(out + 8388608 + idx) = make_float4(o2[0], o2[1], o2[2], o2[3]);
}

// ---------- host ----------
extern "C" void kernel_launch(void* const* d_in, const int* in_sizes, int n_in,
                              void* d_out, int out_size, void* d_ws, size_t ws_size,
                              hipStream_t stream) {
    (void)in_sizes; (void)n_in; (void)out_size; (void)ws_size;
    const float* x1 = (const float*)d_in[0];
    const float* x2 = (const float*)d_in[1];
    const float* wq1 = (const float*)d_in[2];  const float* bq1 = (const float*)d_in[3];
    const float* wq2 = (const float*)d_in[4];  const float* bq2 = (const float*)d_in[5];
    const float* wk1 = (const float*)d_in[6];  const float* bk1 = (const float*)d_in[7];
    const float* wk2 = (const float*)d_in[8];  const float* bk2 = (const float*)d_in[9];
    const float* wv1 = (const float*)d_in[10]; const float* bv1 = (const float*)d_in[11];
    const float* wv2 = (const float*)d_in[12]; const float* bv2 = (const float*)d_in[13];
    const float* gamma1 = (const float*)d_in[14];
    const float* gamma2 = (const float*)d_in[15];
    const float* sc1_w1 = (const float*)d_in[16]; const float* sc1_b1 = (const float*)d_in[17];
    const float* sc1_w2 = (const float*)d_in[18]; const float* sc1_b2 = (const float*)d_in[19];
    const float* sc2_w1 = (const float*)d_in[20]; const float* sc2_b1 = (const float*)d_in[21];
    const float* sc2_w2 = (const float*)d_in[22]; const float* sc2_b2 = (const float*)d_in[23];
    const float* bn1_scale = (const float*)d_in[24]; const float* bn1_bias = (const float*)d_in[25];
    const float* bn2_scale = (const float*)d_in[26]; const float* bn2_bias = (const float*)d_in[27];

    char* p = (char*)d_ws;
    const size_t SZ_QK = 2097152;   // bf16 (B,8,H,W)
    const size_t SZ_V = 16777216;   // bf16 (B,64,H,W)
    const size_t SZ_ST = 524288;    // fp32 (B,H,W)

    // contiguous input block for single-transpose dispatch: q1,k1,q2,k2,v1,v2
    bf16t* q1 = (bf16t*)(p + 0 * SZ_QK);
    bf16t* k1 = (bf16t*)(p + 1 * SZ_QK);
    bf16t* q2 = (bf16t*)(p + 2 * SZ_QK);
    bf16t* k2 = (bf16t*)(p + 3 * SZ_QK);
    bf16t* v1 = (bf16t*)(p + 4 * SZ_QK);
    bf16t* v2 = (bf16t*)(p + 4 * SZ_QK + SZ_V);
    size_t off = 4 * SZ_QK + 2 * SZ_V;
    bf16t* q1T = (bf16t*)(p + off + 0 * SZ_QK);
    bf16t* k1T = (bf16t*)(p + off + 1 * SZ_QK);
    bf16t* q2T = (bf16t*)(p + off + 2 * SZ_QK);
    bf16t* k2T = (bf16t*)(p + off + 3 * SZ_QK);
    bf16t* v1T = (bf16t*)(p + off + 4 * SZ_QK);
    bf16t* v2T = (bf16t*)(p + off + 4 * SZ_QK + SZ_V);
    off += 4 * SZ_QK + 2 * SZ_V;
    bf16t* oH1T = (bf16t*)(p + off); off += SZ_V;
    bf16t* oH2T = (bf16t*)(p + off); off += SZ_V;
    bf16t* oW1 = (bf16t*)(p + off); off += SZ_V;
    bf16t* oW2 = (bf16t*)(p + off); off += SZ_V;
    float* sH1 = (float*)(p + off); off += SZ_ST;   // row-frame (scattered by column pass)
    float* sH2 = (float*)(p + off); off += SZ_ST;
    float* sW1 = (float*)(p + off); off += SZ_ST;
    float* sW2 = (float*)(p + off); off += SZ_ST;
    float* accum = (float*)(p + off);                  // 1280 f32
    unsigned* accmax = (unsigned*)(p + off + 5120);    // 256 u32
    float* gates = (float*)(p + off + 6144);
    float* AB = (float*)(p + off + 7168);

    // overlays (stream-ordered producers precede the overwrite):
    bf16t* oH1 = v1T;   // v1T,v2T dead after rowcc
    bf16t* oH2 = v2T;
    bf16t* s1 = oH1T;   // oH1T,oH2T dead after output transpose
    bf16t* s2 = oH2T;

    // K1: fused convs (+ accum zeroing in block 0)
    ConvArgs CA;
    CA.x[0] = x1; CA.x[1] = x2;
    CA.wq[0] = wq1; CA.wq[1] = wq2; CA.bq[0] = bq1; CA.bq[1] = bq2;
    CA.wk[0] = wk1; CA.wk[1] = wk2; CA.bk[0] = bk1; CA.bk[1] = bk2;
    CA.wv[0] = wv1; CA.wv[1] = wv2; CA.bv[0] = bv1; CA.bv[1] = bv2;
    CA.q[0] = q1; CA.q[1] = q2; CA.k[0] = k1; CA.k[1] = k2;
    CA.v[0] = v1; CA.v[1] = v2;
    CA.zeroR = (unsigned*)accum;
    conv_qkv<<<dim3(4, 64, 4), 256, 0, stream>>>(CA);

    // K2: all input transposes in one dispatch (q1..k2 = 64 slices, v1,v2 = 256)
    transpose16<<<dim3(4, 4, 320), 256, 0, stream>>>(q1, q1T);

    // K3: fused criss-cross
    RowccArgs RA;
    RA.q[0] = q2T; RA.k[0] = k1T; RA.v[0] = v1T; RA.o[0] = oH1T; RA.so[0] = sH1;
    RA.q[1] = q1T; RA.k[1] = k2T; RA.v[1] = v2T; RA.o[1] = oH2T; RA.so[1] = sH2;
    RA.q[2] = q2;  RA.k[2] = k1;  RA.v[2] = v1;  RA.o[2] = oW1;  RA.so[2] = sW1;
    RA.q[3] = q1;  RA.k[3] = k2;  RA.v[3] = v2;  RA.o[3] = oW2;  RA.so[3] = sW2;
    rowcc_mfma<<<dim3(256, 2, 4), 256, 0, stream>>>(RA);

    // K4: output transpose (oH1T,oH2T -> oH1,oH2)
    transpose16<<<dim3(4, 4, 256), 256, 0, stream>>>(oH1T, oH1);

    combine_reduce<<<dim3(16, 64, 2), 256, 0, stream>>>(
        oH1, oW1, oH2, oW2, sH1, sW1, sH2, sW2, x1, x2, gamma1, gamma2,
        s1, s2, accum, accmax);

    gates_bn<<<1, 256, 0, stream>>>(accum, accmax,
                                    sc1_w1, sc1_b1, sc1_w2, sc1_b2,
                                    sc2_w1, sc2_b1, sc2_w2, sc2_b2,
                                    bn1_scale, bn1_bias, bn2_scale, bn2_bias,
                                    gates, AB);

    finalize<<<8192, 256, 0, stream>>>(s1, s2, x1, x2, gates, AB, (float*)d_out);
}

// Round 5
// 323.385 us; speedup vs baseline: 2.0750x; 1.1334x over previous
//
#include <hip/hip_runtime.h>
#include <hip/hip_bf16.h>
#include <cstdint>
#include <cstddef>

typedef unsigned short bf16t;
typedef __attribute__((ext_vector_type(8))) short bf16x8;  // 8 bf16 (4 VGPRs)
typedef __attribute__((ext_vector_type(4))) float f32x4;   // MFMA C/D

// ---------- helpers ----------
__device__ __forceinline__ unsigned short f2bf(float f) {
    unsigned u = __float_as_uint(f);
    u += 0x7fffu + ((u >> 16) & 1u);   // RNE
    return (unsigned short)(u >> 16);
}
__device__ __forceinline__ float bf2f(unsigned short h) {
    return __uint_as_float(((unsigned)h) << 16);
}
__device__ __forceinline__ float bflo(unsigned u) { return __uint_as_float(u << 16); }
__device__ __forceinline__ float bfhi(unsigned u) { return __uint_as_float(u & 0xffff0000u); }
// packed f32x2 -> bf16x2 via v_cvt_pk_bf16_f32
__device__ __forceinline__ unsigned pk2(float a, float b) {
    __hip_bfloat162 h = __float22bfloat162_rn(make_float2(a, b));
    return *(unsigned*)&h;
}
__device__ __forceinline__ bf16x8 mk8(unsigned a, unsigned b, unsigned c, unsigned d) {
    union { uint4 u; bf16x8 v; } cv; cv.u = make_uint4(a, b, c, d); return cv.v;
}

// order-preserving float<->uint encoding for atomicMax
__device__ __forceinline__ unsigned fenc(float f) {
    unsigned u = __float_as_uint(f);
    return (u & 0x80000000u) ? ~u : (u | 0x80000000u);
}
__device__ __forceinline__ float fdec(unsigned u) {
    return __uint_as_float((u & 0x80000000u) ? (u ^ 0x80000000u) : ~u);
}

#define HW 65536

// ---------- K1: MFMA 1x1 conv: Out[80,HW] = W[80,64] * X[64,HW], X/W cast bf16 ----------
// grid (256 px-rows, 1, 4); z = stream*2 + b; block 256 (4 waves).
// Block covers 256 contiguous pixels. A = X^T tile (m=px, k=ch), B = W (n=out, k=ch).
struct ConvArgs {
    const float* x[2];
    const float* wq[2]; const float* bq[2];
    const float* wk[2]; const float* bk[2];
    const float* wv[2]; const float* bv[2];
    bf16t* q[2]; bf16t* k[2]; bf16t* v[2];
    unsigned* zeroR;    // 1536 u32: accum (1280 f32) + accmax (256 u32)
};

__global__ __launch_bounds__(256) void conv_qkv(ConvArgs A)
{
    __shared__ __align__(16) bf16t Xlds[256 * 68];   // [px][ch], stride 68

    const int t = threadIdx.x;
    const int z = blockIdx.z;
    const int s = z >> 1, b = z & 1;
    if (z == 0 && blockIdx.x == 0) {
#pragma unroll
        for (int i = 0; i < 6; i++) A.zeroR[t + i * 256] = 0u;
    }
    const int lane = t & 63, wv = t >> 6, quad = lane >> 4, l16 = lane & 15;
    const int px0 = blockIdx.x * 256;

    // --- load X column (64 ch) for px = px0 + t; pack bf16; stage transposed ---
    const float* xp = A.x[s] + (size_t)b * 64 * HW + px0 + t;
    {
        unsigned xw[32];
#pragma unroll
        for (int c = 0; c < 32; c++)
            xw[c] = pk2(xp[(size_t)(2 * c) * HW], xp[(size_t)(2 * c + 1) * HW]);
#pragma unroll
        for (int g = 0; g < 16; g++)
            *(uint2*)&Xlds[t * 68 + g * 4] = make_uint2(xw[2 * g], xw[2 * g + 1]);
    }

    // --- B-frags (W) + bias + output row pointers: o = ot*16 + l16 ---
    bf16x8 bfr[5][2];
    float bo[5];
    bf16t* obase[5];
#pragma unroll
    for (int ot = 0; ot < 5; ot++) {
        const int o = ot * 16 + l16;
        const float* wrow;
        if (o < 8)       { wrow = A.wq[s] + o * 64;        bo[ot] = A.bq[s][o];
                           obase[ot] = A.q[s] + (size_t)(b * 8 + o) * HW; }
        else if (o < 16) { wrow = A.wk[s] + (o - 8) * 64;  bo[ot] = A.bk[s][o - 8];
                           obase[ot] = A.k[s] + (size_t)(b * 8 + o - 8) * HW; }
        else             { wrow = A.wv[s] + (o - 16) * 64; bo[ot] = A.bv[s][o - 16];
                           obase[ot] = A.v[s] + (size_t)(b * 64 + o - 16) * HW; }
#pragma unroll
        for (int ks = 0; ks < 2; ks++) {
            const float* wp = wrow + ks * 32 + quad * 8;
            bfr[ot][ks] = mk8(pk2(wp[0], wp[1]), pk2(wp[2], wp[3]),
                              pk2(wp[4], wp[5]), pk2(wp[6], wp[7]));
        }
    }

    __syncthreads();

    // --- A-frags (X^T): wave's px band = wv*64 .. +63, 4 m-tiles ---
    bf16x8 afr[4][2];
#pragma unroll
    for (int i = 0; i < 4; i++)
#pragma unroll
        for (int ks = 0; ks < 2; ks++) {
            const int base = (wv * 64 + i * 16 + l16) * 68 + ks * 32 + quad * 8;
            const uint2 lo = *(const uint2*)&Xlds[base];
            const uint2 hi = *(const uint2*)&Xlds[base + 4];
            afr[i][ks] = mk8(lo.x, lo.y, hi.x, hi.y);
        }

    const f32x4 z4 = {0.f, 0.f, 0.f, 0.f};
    f32x4 acc[4][5];
#pragma unroll
    for (int i = 0; i < 4; i++)
#pragma unroll
        for (int ot = 0; ot < 5; ot++) acc[i][ot] = z4;

#pragma unroll
    for (int ks = 0; ks < 2; ks++)
#pragma unroll
        for (int i = 0; i < 4; i++)
#pragma unroll
            for (int ot = 0; ot < 5; ot++)
                acc[i][ot] = __builtin_amdgcn_mfma_f32_16x16x32_bf16(afr[i][ks], bfr[ot][ks], acc[i][ot], 0, 0, 0);

    // --- epilogue: C rows = px (quad*4+r), cols = o (l16); direct 8B stores ---
#pragma unroll
    for (int i = 0; i < 4; i++) {
        const int px = px0 + wv * 64 + i * 16 + quad * 4;
#pragma unroll
        for (int ot = 0; ot < 5; ot++) {
            uint2 u;
            u.x = pk2(acc[i][ot][0] + bo[ot], acc[i][ot][1] + bo[ot]);
            u.y = pk2(acc[i][ot][2] + bo[ot], acc[i][ot][3] + bo[ot]);
            *(uint2*)&obase[ot][px] = u;
        }
    }
}

// ---------- bf16 transpose: per-slice 256x256, 64x64 tiles, z = slice ----------
__global__ __launch_bounds__(256) void transpose16(const bf16t* __restrict__ in, bf16t* __restrict__ out)
{
    __shared__ bf16t tile[64][68];
    const size_t zo = (size_t)blockIdx.z * HW;
    const int i0 = blockIdx.y * 64, j0 = blockIdx.x * 64;
    const int lc = threadIdx.x & 63, rg = threadIdx.x >> 6;
#pragma unroll
    for (int rr = 0; rr < 16; rr++) {
        int row = rg * 16 + rr;
        tile[row][lc] = in[zo + (size_t)(i0 + row) * 256 + j0 + lc];
    }
    __syncthreads();
#pragma unroll
    for (int rr = 0; rr < 16; rr++) {
        int row = rg * 16 + rr;
        out[zo + (size_t)(j0 + row) * 256 + i0 + lc] = tile[lc][row];
    }
}

// ---------- K2: criss-cross rows, all 4 variants, MFMA scores + MFMA PV ----------
// No max-subtraction (scores bounded ~|8|): p = exp(e) directly; denominator
// s = sum(p) accumulated in-thread, reduced once at the end. Column-pass
// variants (z<2) scatter s into row-frame so combine reads coalesced.
struct RowccArgs {
    const bf16t* q[4]; const bf16t* k[4]; const bf16t* v[4];
    bf16t* o[4]; float* so[4];
};

__global__ __launch_bounds__(256, 3) void rowcc_mfma(RowccArgs P)
{
    // LDS: vs[64][264] bf16 (33792) | ps[256][40] bf16 (20480) = 54272 -> 3 blocks/CU
    __shared__ __align__(16) char smem[54272];
    bf16t* vs = (bf16t*)smem;
    bf16t* ps = (bf16t*)(smem + 33792);

    const int t = threadIdx.x;
    const int r = blockIdx.x, b = blockIdx.y, z = blockIdx.z;
    const bool mask = (z < 2);
    const int lane = t & 63, wv = t >> 6, quad = lane >> 4, l16 = lane & 15;
    const int wband = wv * 64;

    const bf16t* qp = P.q[z];
    const bf16t* kp = P.k[z];
    const bf16t* vp = P.v[z];

    // --- stage V as [c][j] (row stride 264) ---
    const size_t vb = (size_t)b * 64 * HW + (size_t)r * 256;
#pragma unroll
    for (int i = 0; i < 8; i++) {
        const int qd = i * 256 + t;
        const int c = qd >> 5, jc = (qd & 31) * 8;
        *(uint4*)&vs[c * 264 + jc] = *(const uint4*)&vp[vb + (size_t)c * HW + jc];
    }

    // --- Q B-frags from global (quad0 lanes only; quads 1-3 are K-zero-pad) ---
    const bf16x8 zfr = {0, 0, 0, 0, 0, 0, 0, 0};
    bf16x8 qfr[4] = {zfr, zfr, zfr, zfr};
    const size_t rowb = (size_t)b * 8 * HW + (size_t)r * 256;
    if (quad == 0) {
#pragma unroll
        for (int wt = 0; wt < 4; wt++) {
            const int w_g = wband + wt * 16 + l16;
#pragma unroll
            for (int ch = 0; ch < 8; ch++)
                qfr[wt][ch] = (short)qp[rowb + (size_t)ch * HW + w_g];
        }
    }

    const f32x4 z4 = {0.f, 0.f, 0.f, 0.f};
    f32x4 acc[4][4];
#pragma unroll
    for (int i = 0; i < 4; i++)
#pragma unroll
        for (int j = 0; j < 4; j++) acc[i][j] = z4;
    float s_t[4] = {0.f, 0.f, 0.f, 0.f};

    // K A-frag prefetch for jt=0
    bf16x8 kcur[2] = {zfr, zfr};
    if (quad == 0) {
#pragma unroll
        for (int jtile = 0; jtile < 2; jtile++)
#pragma unroll
            for (int ch = 0; ch < 8; ch++)
                kcur[jtile][ch] = (short)kp[rowb + (size_t)ch * HW + jtile * 16 + l16];
    }

    __syncthreads();

    for (int jt = 0; jt < 8; jt++) {
        const int j0 = jt * 32;
        // scores: E[m=j][n=w]; lane: col w=l16, rows j=quad*4+reg
        f32x4 e[4][2];
#pragma unroll
        for (int wt = 0; wt < 4; wt++)
#pragma unroll
            for (int jtile = 0; jtile < 2; jtile++)
                e[wt][jtile] = __builtin_amdgcn_mfma_f32_16x16x32_bf16(kcur[jtile], qfr[wt], z4, 0, 0, 0);

        // prefetch next jt's K frags (overlaps with exp/PV below)
        bf16x8 knext[2] = {zfr, zfr};
        if (jt < 7 && quad == 0) {
            const int jn = (jt + 1) * 32;
#pragma unroll
            for (int jtile = 0; jtile < 2; jtile++)
#pragma unroll
                for (int ch = 0; ch < 8; ch++)
                    knext[jtile][ch] = (short)kp[rowb + (size_t)ch * HW + jn + jtile * 16 + l16];
        }

        // diagonal mask (only 2 of 8 jt can contain this wave's diagonal)
        if (mask && (jt >> 1) == wv) {
#pragma unroll
            for (int wt = 0; wt < 4; wt++) {
                const int w_g = wband + wt * 16 + l16;
#pragma unroll
                for (int jtile = 0; jtile < 2; jtile++)
#pragma unroll
                    for (int rr = 0; rr < 4; rr++)
                        if (j0 + jtile * 16 + quad * 4 + rr == w_g) e[wt][jtile][rr] = -3.0e38f;
            }
        }

        // p = exp(e); accumulate denominator; write P to LDS in A-layout
#pragma unroll
        for (int wt = 0; wt < 4; wt++) {
#pragma unroll
            for (int jtile = 0; jtile < 2; jtile++) {
                const float p0 = __expf(e[wt][jtile][0]);
                const float p1 = __expf(e[wt][jtile][1]);
                const float p2 = __expf(e[wt][jtile][2]);
                const float p3 = __expf(e[wt][jtile][3]);
                s_t[wt] += (p0 + p1) + (p2 + p3);
                uint2 u; u.x = pk2(p0, p1); u.y = pk2(p2, p3);
                *(uint2*)&ps[(wband + wt * 16 + l16) * 40 + jtile * 16 + quad * 4] = u;
            }
        }

        // PV: A = P (w x j), B = V (j x c)
        bf16x8 afr[4], bfr[4];
#pragma unroll
        for (int wt = 0; wt < 4; wt++)
            afr[wt] = *(const bf16x8*)&ps[(wband + wt * 16 + l16) * 40 + quad * 8];
#pragma unroll
        for (int ct = 0; ct < 4; ct++)
            bfr[ct] = *(const bf16x8*)&vs[(ct * 16 + l16) * 264 + j0 + quad * 8];
#pragma unroll
        for (int wt = 0; wt < 4; wt++)
#pragma unroll
            for (int ct = 0; ct < 4; ct++)
                acc[wt][ct] = __builtin_amdgcn_mfma_f32_16x16x32_bf16(afr[wt], bfr[ct], acc[wt][ct], 0, 0, 0);

        kcur[0] = knext[0]; kcur[1] = knext[1];
    }

    // denominator: reduce across quads (each quad holds a disjoint j-subset)
#pragma unroll
    for (int wt = 0; wt < 4; wt++) {
        float s = s_t[wt];
        s += __shfl_xor(s, 16, 64);
        s += __shfl_xor(s, 32, 64);
        s_t[wt] = s;
    }
    if (quad == 0) {
#pragma unroll
        for (int wt = 0; wt < 4; wt++) {
            const int w_g = wband + wt * 16 + l16;
            if (mask)  // column pass: pixel (h=w_g, w=r) in row-frame
                P.so[z][(size_t)b * HW + w_g * 256 + r] = s_t[wt];
            else
                P.so[z][(size_t)b * HW + r * 256 + w_g] = s_t[wt];
        }
    }

    // epilogue: C-layout -> LDS [c][w] -> coalesced global [c][w]
    __syncthreads();
    bf16t* o_lds = (bf16t*)smem;   // [64][264], overlays vs
#pragma unroll
    for (int wt = 0; wt < 4; wt++) {
        const int w0 = wband + wt * 16 + quad * 4;
#pragma unroll
        for (int ct = 0; ct < 4; ct++) {
            const int c = ct * 16 + l16;
            uint2 u;
            u.x = pk2(acc[wt][ct][0], acc[wt][ct][1]);
            u.y = pk2(acc[wt][ct][2], acc[wt][ct][3]);
            *(uint2*)&o_lds[c * 264 + w0] = u;
        }
    }
    __syncthreads();
    bf16t* ob = P.o[z] + (size_t)b * 64 * HW + (size_t)r * 256;
#pragma unroll
    for (int i = 0; i < 8; i++) {
        const int qd = i * 256 + t;
        const int c = qd >> 5, w8 = (qd & 31) * 8;
        *(uint4*)&ob[(size_t)c * HW + w8] = *(const uint4*)&o_lds[c * 264 + w8];
    }
}

// ---------- K4: combine att + residuals, write s1/s2 (bf16), reduce stats ----------
__global__ __launch_bounds__(256) void combine_reduce(
    const bf16t* __restrict__ oH1, const bf16t* __restrict__ oW1,
    const bf16t* __restrict__ oH2, const bf16t* __restrict__ oW2,
    const float* __restrict__ sH1, const float* __restrict__ sW1,
    const float* __restrict__ sH2, const float* __restrict__ sW2,
    const float* __restrict__ x1, const float* __restrict__ x2,
    const float* __restrict__ gamma1, const float* __restrict__ gamma2,
    bf16t* __restrict__ s1, bf16t* __restrict__ s2,
    float* __restrict__ accum, unsigned* __restrict__ accmax)
{
    const int t = threadIdx.x, chunk = blockIdx.x, c = blockIdx.y, b = blockIdx.z;
    const float g1v = gamma1[0], g2v = gamma2[0];
    const size_t cb = ((size_t)(b * 64 + c)) * HW;
    const size_t pb = (size_t)b * HW;

    float pS1 = 0, pSS1 = 0, pSX1 = 0, pX1 = 0, pXX1 = 0, pM1 = -3e38f;
    float pS2 = 0, pSS2 = 0, pSX2 = 0, pX2 = 0, pXX2 = 0, pM2 = -3e38f;

    for (int i = 0; i < 16; i++) {
        const int pidx = chunk * 4096 + i * 256 + t;
        const float inv1 = 1.f / (sH1[pb + pidx] + sW1[pb + pidx]);
        const float inv2 = 1.f / (sH2[pb + pidx] + sW2[pb + pidx]);
        const float a1 = (bf2f(oH1[cb + pidx]) + bf2f(oW1[cb + pidx])) * inv1;
        const float a2 = (bf2f(oH2[cb + pidx]) + bf2f(oW2[cb + pidx])) * inv2;
        const float x1v = x1[cb + pidx], x2v = x2[cb + pidx];
        const float s1v = g2v * a2 + x2v + x1v;
        const float s2v = g1v * a1 + x1v + x2v;
        s1[cb + pidx] = f2bf(s1v);
        s2[cb + pidx] = f2bf(s2v);
        pS1 += s1v; pSS1 += s1v * s1v; pSX1 += s1v * x1v; pX1 += x1v; pXX1 += x1v * x1v; pM1 = fmaxf(pM1, s1v);
        pS2 += s2v; pSS2 += s2v * s2v; pSX2 += s2v * x2v; pX2 += x2v; pXX2 += x2v * x2v; pM2 = fmaxf(pM2, s2v);
    }

    __shared__ float wred[12][4];
    float vals[12] = {pS1, pSS1, pSX1, pX1, pXX1, pM1, pS2, pSS2, pSX2, pX2, pXX2, pM2};
    const int lane = t & 63, wave = t >> 6;
#pragma unroll
    for (int iv = 0; iv < 12; iv++) {
        float v = vals[iv];
        const bool isMax = (iv == 5 || iv == 11);
#pragma unroll
        for (int off = 32; off > 0; off >>= 1) {
            const float o = __shfl_down(v, off, 64);
            v = isMax ? fmaxf(v, o) : (v + o);
        }
        if (lane == 0) wred[iv][wave] = v;
    }
    __syncthreads();
    if (t < 12) {
        const bool isMax = (t == 5 || t == 11);
        float v = wred[t][0];
        for (int i = 1; i < 4; i++) v = isMax ? fmaxf(v, wred[t][i]) : (v + wred[t][i]);
        const int stream = (t >= 6) ? 1 : 0;
        const int kk = t - stream * 6;
        if (kk == 5) atomicMax(&accmax[(stream * 2 + b) * 64 + c], fenc(v));
        else atomicAdd(&accum[((stream * 2 + b) * 64 + c) * 5 + kk], v);
    }
}

// ---------- K5: gates (shareca MLP) + analytic BN coefficients ----------
__global__ __launch_bounds__(256) void gates_bn(
    const float* __restrict__ accum, const unsigned* __restrict__ accmax,
    const float* __restrict__ sc1_w1, const float* __restrict__ sc1_b1,
    const float* __restrict__ sc1_w2, const float* __restrict__ sc1_b2,
    const float* __restrict__ sc2_w1, const float* __restrict__ sc2_b1,
    const float* __restrict__ sc2_w2, const float* __restrict__ sc2_b2,
    const float* __restrict__ bn1_scale, const float* __restrict__ bn1_bias,
    const float* __restrict__ bn2_scale, const float* __restrict__ bn2_bias,
    float* __restrict__ gates, float* __restrict__ AB)
{
    const int t = threadIdx.x;
    const int stream = t >> 7, b = (t >> 6) & 1, c = t & 63;
    __shared__ float meanS[256], maxS[256], e1S[256], e2S[256];

    const float S = accum[t * 5 + 0], SS = accum[t * 5 + 1], SX = accum[t * 5 + 2];
    const float X = accum[t * 5 + 3], XX = accum[t * 5 + 4];
    meanS[t] = S * (1.f / 65536.f);
    maxS[t] = fdec(accmax[t]);
    __syncthreads();

    const float* w1 = stream ? sc2_w1 : sc1_w1;
    const float* b1 = stream ? sc2_b1 : sc1_b1;
    const float* w2 = stream ? sc2_w2 : sc1_w2;
    const float* b2 = stream ? sc2_b2 : sc1_b2;
    float om = b2[c], ox = b2[c];
    const int base = stream * 128 + b * 64;
#pragma unroll
    for (int r = 0; r < 4; r++) {
        float hm = b1[r], hx = b1[r];
        for (int cc = 0; cc < 64; cc++) {
            hm += w1[r * 64 + cc] * meanS[base + cc];
            hx += w1[r * 64 + cc] * maxS[base + cc];
        }
        hm = fmaxf(hm, 0.f); hx = fmaxf(hx, 0.f);
        om += w2[c * 4 + r] * hm;
        ox += w2[c * 4 + r] * hx;
    }
    const float gate = 1.f / (1.f + __expf(-(om + ox)));
    gates[t] = gate;
    e1S[t] = gate * S + X;
    e2S[t] = gate * gate * SS + 2.f * gate * SX + XX;
    __syncthreads();
    if (b == 0) {
        const float sumY = e1S[t] + e1S[t + 64];
        const float sumY2 = e2S[t] + e2S[t + 64];
        const float meanY = sumY * (1.f / 131072.f);
        const float varY = sumY2 * (1.f / 131072.f) - meanY * meanY;
        const float sc = stream ? bn2_scale[c] : bn1_scale[c];
        const float bi = stream ? bn2_bias[c] : bn1_bias[c];
        const float A = sc * rsqrtf(varY + 1e-5f);
        AB[stream * 128 + c] = A;
        AB[stream * 128 + 64 + c] = bi - meanY * A;
    }
}

// ---------- K6: final elementwise ----------
__global__ __launch_bounds__(256) void finalize(
    const bf16t* __restrict__ s1, const bf16t* __restrict__ s2,
    const float* __restrict__ x1, const float* __restrict__ x2,
    const float* __restrict__ gates, const float* __restrict__ AB,
    float* __restrict__ out)
{
    const size_t tid = (size_t)blockIdx.x * 256 + threadIdx.x;
    const size_t idx = tid * 4;
    const int b = (int)(idx >> 22);
    const int c = (int)((idx >> 16) & 63);
    const bool odd = (c & 1) != 0;
    const float g1 = gates[b * 64 + c], g2 = gates[128 + b * 64 + c];
    const float A1 = AB[c], B1 = AB[64 + c], A2 = AB[128 + c], B2 = AB[192 + c];

    const uint2 su1 = *(const uint2*)(s1 + idx);
    const uint2 su2 = *(const uint2*)(s2 + idx);
    const float4 x1v = *(const float4*)(x1 + idx);
    const float4 x2v = *(const float4*)(x2 + idx);
    float s1f[4] = {bflo(su1.x), bfhi(su1.x), bflo(su1.y), bfhi(su1.y)};
    float s2f[4] = {bflo(su2.x), bfhi(su2.x), bflo(su2.y), bfhi(su2.y)};
    float xa[4] = {x1v.x, x1v.y, x1v.z, x1v.w};
    float xb[4] = {x2v.x, x2v.y, x2v.z, x2v.w};
    float o1[4], o2[4];
#pragma unroll
    for (int j = 0; j < 4; j++) {
        const float y1 = g1 * s1f[j] + xa[j];
        const float y2 = g2 * s2f[j] + xb[j];
        o1[j] = odd ? fmaxf(A1 * y1 + B1, 0.f) : xa[j];
        o2[j] = odd ? fmaxf(A2 * y2 + B2, 0.f) : xb[j];
    }
    *(float4*)(out + idx) = make_float4(o1[0], o1[1], o1[2], o1[3]);
    *(float4*)(out + 8388608 + idx) = make_float4(o2[0], o2[1], o2[2], o2[3]);
}

// ---------- host ----------
extern "C" void kernel_launch(void* const* d_in, const int* in_sizes, int n_in,
                              void* d_out, int out_size, void* d_ws, size_t ws_size,
                              hipStream_t stream) {
    (void)in_sizes; (void)n_in; (void)out_size; (void)ws_size;
    const float* x1 = (const float*)d_in[0];
    const float* x2 = (const float*)d_in[1];
    const float* wq1 = (const float*)d_in[2];  const float* bq1 = (const float*)d_in[3];
    const float* wq2 = (const float*)d_in[4];  const float* bq2 = (const float*)d_in[5];
    const float* wk1 = (const float*)d_in[6];  const float* bk1 = (const float*)d_in[7];
    const float* wk2 = (const float*)d_in[8];  const float* bk2 = (const float*)d_in[9];
    const float* wv1 = (const float*)d_in[10]; const float* bv1 = (const float*)d_in[11];
    const float* wv2 = (const float*)d_in[12]; const float* bv2 = (const float*)d_in[13];
    const float* gamma1 = (const float*)d_in[14];
    const float* gamma2 = (const float*)d_in[15];
    const float* sc1_w1 = (const float*)d_in[16]; const float* sc1_b1 = (const float*)d_in[17];
    const float* sc1_w2 = (const float*)d_in[18]; const float* sc1_b2 = (const float*)d_in[19];
    const float* sc2_w1 = (const float*)d_in[20]; const float* sc2_b1 = (const float*)d_in[21];
    const float* sc2_w2 = (const float*)d_in[22]; const float* sc2_b2 = (const float*)d_in[23];
    const float* bn1_scale = (const float*)d_in[24]; const float* bn1_bias = (const float*)d_in[25];
    const float* bn2_scale = (const float*)d_in[26]; const float* bn2_bias = (const float*)d_in[27];

    char* p = (char*)d_ws;
    const size_t SZ_QK = 2097152;   // bf16 (B,8,H,W)
    const size_t SZ_V = 16777216;   // bf16 (B,64,H,W)
    const size_t SZ_ST = 524288;    // fp32 (B,H,W)

    // contiguous input block for single-transpose dispatch: q1,k1,q2,k2,v1,v2
    bf16t* q1 = (bf16t*)(p + 0 * SZ_QK);
    bf16t* k1 = (bf16t*)(p + 1 * SZ_QK);
    bf16t* q2 = (bf16t*)(p + 2 * SZ_QK);
    bf16t* k2 = (bf16t*)(p + 3 * SZ_QK);
    bf16t* v1 = (bf16t*)(p + 4 * SZ_QK);
    bf16t* v2 = (bf16t*)(p + 4 * SZ_QK + SZ_V);
    size_t off = 4 * SZ_QK + 2 * SZ_V;
    bf16t* q1T = (bf16t*)(p + off + 0 * SZ_QK);
    bf16t* k1T = (bf16t*)(p + off + 1 * SZ_QK);
    bf16t* q2T = (bf16t*)(p + off + 2 * SZ_QK);
    bf16t* k2T = (bf16t*)(p + off + 3 * SZ_QK);
    bf16t* v1T = (bf16t*)(p + off + 4 * SZ_QK);
    bf16t* v2T = (bf16t*)(p + off + 4 * SZ_QK + SZ_V);
    off += 4 * SZ_QK + 2 * SZ_V;
    bf16t* oH1T = (bf16t*)(p + off); off += SZ_V;
    bf16t* oH2T = (bf16t*)(p + off); off += SZ_V;
    bf16t* oW1 = (bf16t*)(p + off); off += SZ_V;
    bf16t* oW2 = (bf16t*)(p + off); off += SZ_V;
    float* sH1 = (float*)(p + off); off += SZ_ST;   // row-frame (scattered by column pass)
    float* sH2 = (float*)(p + off); off += SZ_ST;
    float* sW1 = (float*)(p + off); off += SZ_ST;
    float* sW2 = (float*)(p + off); off += SZ_ST;
    float* accum = (float*)(p + off);                  // 1280 f32
    unsigned* accmax = (unsigned*)(p + off + 5120);    // 256 u32
    float* gates = (float*)(p + off + 6144);
    float* AB = (float*)(p + off + 7168);

    // overlays (stream-ordered producers precede the overwrite):
    bf16t* oH1 = v1T;   // v1T,v2T dead after rowcc
    bf16t* oH2 = v2T;
    bf16t* s1 = oH1T;   // oH1T,oH2T dead after output transpose
    bf16t* s2 = oH2T;

    // K1: MFMA convs (+ accum zeroing in block 0)
    ConvArgs CA;
    CA.x[0] = x1; CA.x[1] = x2;
    CA.wq[0] = wq1; CA.wq[1] = wq2; CA.bq[0] = bq1; CA.bq[1] = bq2;
    CA.wk[0] = wk1; CA.wk[1] = wk2; CA.bk[0] = bk1; CA.bk[1] = bk2;
    CA.wv[0] = wv1; CA.wv[1] = wv2; CA.bv[0] = bv1; CA.bv[1] = bv2;
    CA.q[0] = q1; CA.q[1] = q2; CA.k[0] = k1; CA.k[1] = k2;
    CA.v[0] = v1; CA.v[1] = v2;
    CA.zeroR = (unsigned*)accum;
    conv_qkv<<<dim3(256, 1, 4), 256, 0, stream>>>(CA);

    // K2: all input transposes in one dispatch (q1..k2 = 64 slices, v1,v2 = 256)
    transpose16<<<dim3(4, 4, 320), 256, 0, stream>>>(q1, q1T);

    // K3: fused criss-cross
    RowccArgs RA;
    RA.q[0] = q2T; RA.k[0] = k1T; RA.v[0] = v1T; RA.o[0] = oH1T; RA.so[0] = sH1;
    RA.q[1] = q1T; RA.k[1] = k2T; RA.v[1] = v2T; RA.o[1] = oH2T; RA.so[1] = sH2;
    RA.q[2] = q2;  RA.k[2] = k1;  RA.v[2] = v1;  RA.o[2] = oW1;  RA.so[2] = sW1;
    RA.q[3] = q1;  RA.k[3] = k2;  RA.v[3] = v2;  RA.o[3] = oW2;  RA.so[3] = sW2;
    rowcc_mfma<<<dim3(256, 2, 4), 256, 0, stream>>>(RA);

    // K4: output transpose (oH1T,oH2T -> oH1,oH2)
    transpose16<<<dim3(4, 4, 256), 256, 0, stream>>>(oH1T, oH1);

    combine_reduce<<<dim3(16, 64, 2), 256, 0, stream>>>(
        oH1, oW1, oH2, oW2, sH1, sW1, sH2, sW2, x1, x2, gamma1, gamma2,
        s1, s2, accum, accmax);

    gates_bn<<<1, 256, 0, stream>>>(accum, accmax,
                                    sc1_w1, sc1_b1, sc1_w2, sc1_b2,
                                    sc2_w1, sc2_b1, sc2_w2, sc2_b2,
                                    bn1_scale, bn1_bias, bn2_scale, bn2_bias,
                                    gates, AB);

    finalize<<<8192, 256, 0, stream>>>(s1, s2, x1, x2, gates, AB, (float*)d_out);
}